// Round 1
// baseline (3346.326 us; speedup 1.0000x reference)
//
#include <hip/hip_runtime.h>
#include <math.h>

#define D 128
#define NH 8
#define DHH 16
#define DFF 512
#define NG 64
#define NL 4
#define FIN 100
#define SCALE 0.25f

// ---------------- CSR build ----------------
__global__ void count_kernel(const int* __restrict__ dst, int* __restrict__ cnt, int E) {
    int e = blockIdx.x * 256 + threadIdx.x;
    if (e < E) atomicAdd(&cnt[dst[e]], 1);
}

__global__ __launch_bounds__(1024) void scan_block_kernel(const int* __restrict__ cnt,
        int* __restrict__ incl, int* __restrict__ partials, int n) {
    __shared__ int s[1024];
    int tid = threadIdx.x;
    int gid = blockIdx.x * 1024 + tid;
    int val = (gid < n) ? cnt[gid] : 0;
    s[tid] = val;
    __syncthreads();
    for (int o = 1; o < 1024; o <<= 1) {
        int t = (tid >= o) ? s[tid - o] : 0;
        __syncthreads();
        s[tid] += t;
        __syncthreads();
    }
    if (gid < n) incl[gid] = s[tid];
    if (tid == 1023) partials[blockIdx.x] = s[1023];
}

__global__ void scan_partials_kernel(int* __restrict__ partials, int nb) {
    if (threadIdx.x == 0 && blockIdx.x == 0) {
        int run = 0;
        for (int i = 0; i < nb; ++i) { int t = partials[i]; partials[i] = run; run += t; }
    }
}

__global__ void finalize_off_kernel(const int* __restrict__ cnt, const int* __restrict__ incl,
        const int* __restrict__ partials, int* __restrict__ off, int* __restrict__ cur,
        int n, int E) {
    int gid = blockIdx.x * 256 + threadIdx.x;
    if (gid < n) {
        int v = incl[gid] - cnt[gid] + partials[gid >> 10];
        off[gid] = v;
        cur[gid] = v;
    }
    if (gid == 0) off[n] = E;
}

__global__ void scatter_kernel(const int* __restrict__ src, const int* __restrict__ dst,
        int* __restrict__ cur, int* __restrict__ csr_src, int E) {
    int e = blockIdx.x * 256 + threadIdx.x;
    if (e < E) {
        int p = atomicAdd(&cur[dst[e]], 1);
        csr_src[p] = src[e];
    }
}

// ---------------- fp32 tiled GEMM: C[M,N] (+= res/bias) = A[M,K] @ B[K,N] ----------------
template<bool BIAS, bool RES>
__global__ __launch_bounds__(256) void gemm64(const float* __restrict__ A,
        const float* __restrict__ B, const float* __restrict__ bias,
        float* __restrict__ C, int M, int N, int K) {
    __shared__ float As[64][33];
    __shared__ float Bs[32][65];
    int t = threadIdx.x;
    int row0 = blockIdx.x * 64, col0 = blockIdx.y * 64;
    int tx = t & 15, ty = t >> 4;
    float acc[4][4] = {};
    for (int k0 = 0; k0 < K; k0 += 32) {
#pragma unroll
        for (int i = 0; i < 8; ++i) {
            int idx = t + i * 256;
            int r = idx >> 5, kk = idx & 31;
            int gr = row0 + r, gk = k0 + kk;
            As[r][kk] = (gr < M && gk < K) ? A[(size_t)gr * K + gk] : 0.f;
        }
#pragma unroll
        for (int i = 0; i < 8; ++i) {
            int idx = t + i * 256;
            int kk = idx >> 6, c = idx & 63;
            int gk = k0 + kk;
            Bs[kk][c] = (gk < K) ? B[(size_t)gk * N + col0 + c] : 0.f;
        }
        __syncthreads();
#pragma unroll
        for (int kk = 0; kk < 32; ++kk) {
            float b0 = Bs[kk][tx * 4 + 0];
            float b1v = Bs[kk][tx * 4 + 1];
            float b2v = Bs[kk][tx * 4 + 2];
            float b3v = Bs[kk][tx * 4 + 3];
#pragma unroll
            for (int r = 0; r < 4; ++r) {
                float a = As[ty * 4 + r][kk];
                acc[r][0] += a * b0;
                acc[r][1] += a * b1v;
                acc[r][2] += a * b2v;
                acc[r][3] += a * b3v;
            }
        }
        __syncthreads();
    }
#pragma unroll
    for (int r = 0; r < 4; ++r) {
        int gr = row0 + ty * 4 + r;
        if (gr < M) {
#pragma unroll
            for (int i = 0; i < 4; ++i) {
                int gc = col0 + tx * 4 + i;
                float v = acc[r][i];
                if (BIAS) v += bias[gc];
                if (RES) v += C[(size_t)gr * N + gc];
                C[(size_t)gr * N + gc] = v;
            }
        }
    }
}

// ---------------- attention: wave per dst node, 2-pass segment softmax ----------------
__global__ __launch_bounds__(256) void attn_kernel(const float* __restrict__ qk,
        const float* __restrict__ v, const int* __restrict__ off,
        const int* __restrict__ csr_src, float* __restrict__ agg, int n) {
    int wave = threadIdx.x >> 6;
    int lane = threadIdx.x & 63;
    int i = blockIdx.x * 4 + wave;
    if (i >= n) return;
    int d0 = lane * 2;
    float2 k2 = *reinterpret_cast<const float2*>(qk + (size_t)i * 256 + 128 + d0);
    int e0 = off[i], e1 = off[i + 1];
    float m = -INFINITY;
    for (int e = e0; e < e1; ++e) {
        int s = csr_src[e];
        float2 q2 = *reinterpret_cast<const float2*>(qk + (size_t)s * 256 + d0);
        float part = q2.x * k2.x + q2.y * k2.y;
        part += __shfl_xor(part, 1);
        part += __shfl_xor(part, 2);
        part += __shfl_xor(part, 4);
        m = fmaxf(m, part * SCALE);
    }
    float ssum = 0.f, ax = 0.f, ay = 0.f;
    for (int e = e0; e < e1; ++e) {
        int s = csr_src[e];
        float2 q2 = *reinterpret_cast<const float2*>(qk + (size_t)s * 256 + d0);
        float part = q2.x * k2.x + q2.y * k2.y;
        part += __shfl_xor(part, 1);
        part += __shfl_xor(part, 2);
        part += __shfl_xor(part, 4);
        float p = expf(part * SCALE - m);
        ssum += p;
        float2 v2 = *reinterpret_cast<const float2*>(v + (size_t)s * 128 + d0);
        ax += p * v2.x;
        ay += p * v2.y;
    }
    float inv = (e1 > e0) ? 1.f / ssum : 0.f;
    float2 outv = make_float2(ax * inv, ay * inv);
    *reinterpret_cast<float2*>(agg + (size_t)i * 128 + d0) = outv;
}

// ---------------- fused FFN: h = h + relu(h@W1+b1)@W2 + b2, 16 rows/block ----------------
__global__ __launch_bounds__(256) void ffn_kernel(float* __restrict__ h,
        const float* __restrict__ W1, const float* __restrict__ b1,
        const float* __restrict__ W2, const float* __restrict__ b2, int M) {
    __shared__ float hs[16][128];
    __shared__ float fs[16][512];
    int t = threadIdx.x;
    int row0 = blockIdx.x * 16;
#pragma unroll
    for (int i = 0; i < 8; ++i) {
        int idx = t + i * 256;
        int r = idx >> 7, c = idx & 127;
        int gr = row0 + r;
        hs[r][c] = (gr < M) ? h[(size_t)gr * 128 + c] : 0.f;
    }
    __syncthreads();
    // phase 1: fs[r][j] = relu(hs[r,:] @ W1[:,j] + b1[j]); thread owns j = t and t+256
    float acc1a[16], acc1b[16];
#pragma unroll
    for (int r = 0; r < 16; ++r) { acc1a[r] = 0.f; acc1b[r] = 0.f; }
    for (int k = 0; k < 128; k += 4) {
        float w0[4], w1[4];
#pragma unroll
        for (int kk = 0; kk < 4; ++kk) {
            w0[kk] = W1[(size_t)(k + kk) * 512 + t];
            w1[kk] = W1[(size_t)(k + kk) * 512 + t + 256];
        }
#pragma unroll
        for (int r = 0; r < 16; ++r) {
            float4 hv = *reinterpret_cast<const float4*>(&hs[r][k]);
            acc1a[r] += hv.x * w0[0] + hv.y * w0[1] + hv.z * w0[2] + hv.w * w0[3];
            acc1b[r] += hv.x * w1[0] + hv.y * w1[1] + hv.z * w1[2] + hv.w * w1[3];
        }
    }
    float b1a = b1[t], b1b = b1[t + 256];
#pragma unroll
    for (int r = 0; r < 16; ++r) {
        fs[r][t] = fmaxf(acc1a[r] + b1a, 0.f);
        fs[r][t + 256] = fmaxf(acc1b[r] + b1b, 0.f);
    }
    __syncthreads();
    // phase 2: out[r][c] = hs[r][c] + fs[r,:] @ W2[:,c] + b2[c]
    // thread owns cols c0,c0+1 and 4 rows
    int c0 = (t & 63) * 2;
    int rbase = (t >> 6) * 4;
    float acc2a[4] = {}, acc2b[4] = {};
    for (int k = 0; k < 512; k += 4) {
        float wa[4], wb[4];
#pragma unroll
        for (int kk = 0; kk < 4; ++kk) {
            float2 w = *reinterpret_cast<const float2*>(&W2[(size_t)(k + kk) * 128 + c0]);
            wa[kk] = w.x;
            wb[kk] = w.y;
        }
#pragma unroll
        for (int rr = 0; rr < 4; ++rr) {
            float4 fv = *reinterpret_cast<const float4*>(&fs[rbase + rr][k]);
            acc2a[rr] += fv.x * wa[0] + fv.y * wa[1] + fv.z * wa[2] + fv.w * wa[3];
            acc2b[rr] += fv.x * wb[0] + fv.y * wb[1] + fv.z * wb[2] + fv.w * wb[3];
        }
    }
    float b2a = b2[c0], b2b = b2[c0 + 1];
#pragma unroll
    for (int rr = 0; rr < 4; ++rr) {
        int gr = row0 + rbase + rr;
        if (gr < M) {
            h[(size_t)gr * 128 + c0] = hs[rbase + rr][c0] + acc2a[rr] + b2a;
            h[(size_t)gr * 128 + c0 + 1] = hs[rbase + rr][c0 + 1] + acc2b[rr] + b2b;
        }
    }
}

// ---------------- pooling ----------------
__global__ void pool_kernel(const float* __restrict__ h, const int* __restrict__ batch,
        float* __restrict__ out, int* __restrict__ gcnt, int n) {
    int node = blockIdx.x * 2 + (threadIdx.x >> 7);
    int c = threadIdx.x & 127;
    if (node >= n) return;
    int g = batch[node];
    atomicAdd(&out[(size_t)g * 128 + c], h[(size_t)node * 128 + c]);
    if (c == 0) atomicAdd(&gcnt[g], 1);
}

__global__ void divide_kernel(float* __restrict__ out, const int* __restrict__ gcnt, int total) {
    int idx = blockIdx.x * 256 + threadIdx.x;
    if (idx < total) {
        int g = idx >> 7;
        out[idx] /= fmaxf((float)gcnt[g], 1.f);
    }
}

extern "C" void kernel_launch(void* const* d_in, const int* in_sizes, int n_in,
                              void* d_out, int out_size, void* d_ws, size_t ws_size,
                              hipStream_t stream) {
    const float* x = (const float*)d_in[0];
    const int* ei = (const int*)d_in[1];
    const int* batch = (const int*)d_in[2];
    const float* W_embed = (const float*)d_in[3];
    const float* Wqk = (const float*)d_in[4];
    const float* Wv = (const float*)d_in[5];
    const float* Wout = (const float*)d_in[6];
    const float* b_out = (const float*)d_in[7];
    const float* W1 = (const float*)d_in[8];
    const float* b1 = (const float*)d_in[9];
    const float* W2 = (const float*)d_in[10];
    const float* b2 = (const float*)d_in[11];

    int Nn = in_sizes[2];
    int E = in_sizes[1] / 2;

    char* p = (char*)d_ws;
    auto alloc = [&](size_t bytes) {
        char* r = p;
        p += (bytes + 255) & ~(size_t)255;
        return r;
    };
    float* h = (float*)alloc((size_t)Nn * D * 4);
    float* qk = (float*)alloc((size_t)Nn * 2 * D * 4);
    float* v = (float*)alloc((size_t)Nn * D * 4);
    float* agg = (float*)alloc((size_t)Nn * D * 4);
    int* csr_src = (int*)alloc((size_t)E * 4);
    int* cnt = (int*)alloc((size_t)Nn * 4);
    int* incl = (int*)alloc((size_t)Nn * 4);
    int* off = (int*)alloc(((size_t)Nn + 1) * 4);
    int* cur = (int*)alloc((size_t)Nn * 4);
    int* partials = (int*)alloc(1024 * 4);
    int* gcnt = (int*)alloc(256 * 4);

    const int* e_src = ei;
    const int* e_dst = ei + E;

    // CSR build (by dst)
    hipMemsetAsync(cnt, 0, (size_t)Nn * 4, stream);
    count_kernel<<<(E + 255) / 256, 256, 0, stream>>>(e_dst, cnt, E);
    int nsb = (Nn + 1023) / 1024;
    scan_block_kernel<<<nsb, 1024, 0, stream>>>(cnt, incl, partials, Nn);
    scan_partials_kernel<<<1, 64, 0, stream>>>(partials, nsb);
    finalize_off_kernel<<<(Nn + 255) / 256, 256, 0, stream>>>(cnt, incl, partials, off, cur, Nn, E);
    scatter_kernel<<<(E + 255) / 256, 256, 0, stream>>>(e_src, e_dst, cur, csr_src, E);

    int gmb = (Nn + 63) / 64;
    // embed: h = x @ W_embed
    gemm64<false, false><<<dim3(gmb, D / 64), 256, 0, stream>>>(x, W_embed, nullptr, h, Nn, D, FIN);

    for (int l = 0; l < NL; ++l) {
        gemm64<false, false><<<dim3(gmb, 2 * D / 64), 256, 0, stream>>>(
            h, Wqk + (size_t)l * D * 2 * D, nullptr, qk, Nn, 2 * D, D);
        gemm64<false, false><<<dim3(gmb, D / 64), 256, 0, stream>>>(
            h, Wv + (size_t)l * D * D, nullptr, v, Nn, D, D);
        attn_kernel<<<(Nn + 3) / 4, 256, 0, stream>>>(qk, v, off, csr_src, agg, Nn);
        gemm64<true, true><<<dim3(gmb, D / 64), 256, 0, stream>>>(
            agg, Wout + (size_t)l * D * D, b_out + (size_t)l * D, h, Nn, D, D);
        ffn_kernel<<<(Nn + 15) / 16, 256, 0, stream>>>(
            h, W1 + (size_t)l * D * DFF, b1 + (size_t)l * DFF,
            W2 + (size_t)l * DFF * D, b2 + (size_t)l * D, Nn);
    }

    hipMemsetAsync(d_out, 0, (size_t)NG * D * 4, stream);
    hipMemsetAsync(gcnt, 0, NG * 4, stream);
    pool_kernel<<<(Nn + 1) / 2, 256, 0, stream>>>(h, batch, (float*)d_out, gcnt, Nn);
    divide_kernel<<<(NG * D + 255) / 256, 256, 0, stream>>>((float*)d_out, gcnt, NG * D);
}

// Round 2
// 1417.059 us; speedup vs baseline: 2.3615x; 2.3615x over previous
//
#include <hip/hip_runtime.h>
#include <hip/hip_bf16.h>
#include <math.h>

#define D 128
#define NH 8
#define DFF 512
#define NG 64
#define NL 4
#define FIN 100
#define SCALE 0.25f

typedef __attribute__((ext_vector_type(8))) short short8;
typedef __attribute__((ext_vector_type(4))) float f32x4;

// ---------------- CSR build ----------------
__global__ void count_kernel(const int* __restrict__ dst, int* __restrict__ cnt, int E) {
    int e = blockIdx.x * 256 + threadIdx.x;
    if (e < E) atomicAdd(&cnt[dst[e]], 1);
}

__global__ __launch_bounds__(1024) void scan_block_kernel(const int* __restrict__ cnt,
        int* __restrict__ incl, int* __restrict__ partials, int n) {
    __shared__ int s[1024];
    int tid = threadIdx.x;
    int gid = blockIdx.x * 1024 + tid;
    int val = (gid < n) ? cnt[gid] : 0;
    s[tid] = val;
    __syncthreads();
    for (int o = 1; o < 1024; o <<= 1) {
        int t = (tid >= o) ? s[tid - o] : 0;
        __syncthreads();
        s[tid] += t;
        __syncthreads();
    }
    if (gid < n) incl[gid] = s[tid];
    if (tid == 1023) partials[blockIdx.x] = s[1023];
}

__global__ void scan_partials_kernel(int* __restrict__ partials, int nb) {
    if (threadIdx.x == 0 && blockIdx.x == 0) {
        int run = 0;
        for (int i = 0; i < nb; ++i) { int t = partials[i]; partials[i] = run; run += t; }
    }
}

__global__ void finalize_off_kernel(const int* __restrict__ cnt, const int* __restrict__ incl,
        const int* __restrict__ partials, int* __restrict__ off, int* __restrict__ cur,
        int n, int E) {
    int gid = blockIdx.x * 256 + threadIdx.x;
    if (gid < n) {
        int v = incl[gid] - cnt[gid] + partials[gid >> 10];
        off[gid] = v;
        cur[gid] = v;
    }
    if (gid == 0) off[n] = E;
}

__global__ void scatter_kernel(const int* __restrict__ src, const int* __restrict__ dst,
        int* __restrict__ cur, int* __restrict__ csr_src, int E) {
    int e = blockIdx.x * 256 + threadIdx.x;
    if (e < E) {
        int p = atomicAdd(&cur[dst[e]], 1);
        csr_src[p] = src[e];
    }
}

// ---------------- weight transpose + bf16 convert: W[K][N] -> Bt[N][K], per layer ----------------
__global__ void transpose_cvt_kernel(const float* __restrict__ W, __hip_bfloat16* __restrict__ Bt,
        int K, int N) {
    int l = blockIdx.y;
    const float* w = W + (size_t)l * K * N;
    __hip_bfloat16* bt = Bt + (size_t)l * K * N;
    int idx = blockIdx.x * 256 + threadIdx.x;
    if (idx >= K * N) return;
    int n = idx / K, k = idx - n * K;
    bt[idx] = __float2bfloat16(w[(size_t)k * N + n]);
}

// ---------------- f32 -> bf16 vector convert ----------------
__global__ void cvt_kernel(const float* __restrict__ in, __hip_bfloat16* __restrict__ out, int n4) {
    int i = blockIdx.x * 256 + threadIdx.x;
    if (i < n4) {
        float4 v = reinterpret_cast<const float4*>(in)[i];
        out[i * 4 + 0] = __float2bfloat16(v.x);
        out[i * 4 + 1] = __float2bfloat16(v.y);
        out[i * 4 + 2] = __float2bfloat16(v.z);
        out[i * 4 + 3] = __float2bfloat16(v.w);
    }
}

// ---------------- fp32 tiled GEMM (embed only, K=100) ----------------
template<bool BIAS, bool RES>
__global__ __launch_bounds__(256) void gemm64(const float* __restrict__ A,
        const float* __restrict__ B, const float* __restrict__ bias,
        float* __restrict__ C, int M, int N, int K) {
    __shared__ float As[64][33];
    __shared__ float Bs[32][65];
    int t = threadIdx.x;
    int row0 = blockIdx.x * 64, col0 = blockIdx.y * 64;
    int tx = t & 15, ty = t >> 4;
    float acc[4][4] = {};
    for (int k0 = 0; k0 < K; k0 += 32) {
#pragma unroll
        for (int i = 0; i < 8; ++i) {
            int idx = t + i * 256;
            int r = idx >> 5, kk = idx & 31;
            int gr = row0 + r, gk = k0 + kk;
            As[r][kk] = (gr < M && gk < K) ? A[(size_t)gr * K + gk] : 0.f;
        }
#pragma unroll
        for (int i = 0; i < 8; ++i) {
            int idx = t + i * 256;
            int kk = idx >> 6, c = idx & 63;
            int gk = k0 + kk;
            Bs[kk][c] = (gk < K) ? B[(size_t)gk * N + col0 + c] : 0.f;
        }
        __syncthreads();
#pragma unroll
        for (int kk = 0; kk < 32; ++kk) {
            float b0 = Bs[kk][tx * 4 + 0];
            float b1v = Bs[kk][tx * 4 + 1];
            float b2v = Bs[kk][tx * 4 + 2];
            float b3v = Bs[kk][tx * 4 + 3];
#pragma unroll
            for (int r = 0; r < 4; ++r) {
                float a = As[ty * 4 + r][kk];
                acc[r][0] += a * b0;
                acc[r][1] += a * b1v;
                acc[r][2] += a * b2v;
                acc[r][3] += a * b3v;
            }
        }
        __syncthreads();
    }
#pragma unroll
    for (int r = 0; r < 4; ++r) {
        int gr = row0 + ty * 4 + r;
        if (gr < M) {
#pragma unroll
            for (int i = 0; i < 4; ++i) {
                int gc = col0 + tx * 4 + i;
                float v = acc[r][i];
                if (BIAS) v += bias[gc];
                if (RES) v += C[(size_t)gr * N + gc];
                C[(size_t)gr * N + gc] = v;
            }
        }
    }
}

// ---------------- bf16 MFMA GEMM: ops(A[M,K] @ Bt[N,K]^T), tile 128x64, BK=64 ----------------
// EPI 0: Cf[row][col] = acc                      (fp32 out)
// EPI 1: Cb = bf16(relu(acc + bias))             (bf16 out)
// EPI 2: v = Cf + acc + bias; Cf = v; Cb = bf16(v)  (residual, dual write)
template<int EPI>
__global__ __launch_bounds__(256) void gemm_mfma(
        const __hip_bfloat16* __restrict__ A, const __hip_bfloat16* __restrict__ Bt,
        const float* __restrict__ bias,
        float* __restrict__ Cf, __hip_bfloat16* __restrict__ Cb,
        int M, int N, int K) {
    __shared__ __align__(16) unsigned short As[128][64];
    __shared__ __align__(16) unsigned short Bs[64][64];
    int t = threadIdx.x;
    int wave = t >> 6, lane = t & 63;
    int row0 = blockIdx.x * 128, col0 = blockIdx.y * 64;
    f32x4 acc[2][4] = {};

    int sr = t >> 3;       // staging row within 32-row slab
    int sc = t & 7;        // staging 16B chunk 0..7

    for (int k0 = 0; k0 < K; k0 += 64) {
#pragma unroll
        for (int i = 0; i < 4; ++i) {
            int r = i * 32 + sr;
            int gr = row0 + r;
            if (gr >= M) gr = M - 1;
            *reinterpret_cast<short8*>(&As[r][(sc ^ (r & 7)) << 3]) =
                *reinterpret_cast<const short8*>(&A[(size_t)gr * K + k0 + (sc << 3)]);
        }
#pragma unroll
        for (int i = 0; i < 2; ++i) {
            int r = i * 32 + sr;
            *reinterpret_cast<short8*>(&Bs[r][(sc ^ (r & 7)) << 3]) =
                *reinterpret_cast<const short8*>(&Bt[(size_t)(col0 + r) * K + k0 + (sc << 3)]);
        }
        __syncthreads();
#pragma unroll
        for (int kk = 0; kk < 64; kk += 32) {
            int lr = lane & 15;
            int kc = (kk >> 3) + (lane >> 4);   // k-chunk index
            short8 a[2], b[4];
#pragma unroll
            for (int m = 0; m < 2; ++m) {
                int r = wave * 32 + m * 16 + lr;
                a[m] = *reinterpret_cast<const short8*>(&As[r][(kc ^ (r & 7)) << 3]);
            }
#pragma unroll
            for (int n = 0; n < 4; ++n) {
                int r = n * 16 + lr;
                b[n] = *reinterpret_cast<const short8*>(&Bs[r][(kc ^ (r & 7)) << 3]);
            }
#pragma unroll
            for (int m = 0; m < 2; ++m)
#pragma unroll
                for (int n = 0; n < 4; ++n)
                    acc[m][n] = __builtin_amdgcn_mfma_f32_16x16x32_bf16(a[m], b[n], acc[m][n], 0, 0, 0);
        }
        __syncthreads();
    }

    int lr = lane & 15, rg = (lane >> 4) * 4;
#pragma unroll
    for (int m = 0; m < 2; ++m) {
#pragma unroll
        for (int n = 0; n < 4; ++n) {
            int col = col0 + n * 16 + lr;
#pragma unroll
            for (int j = 0; j < 4; ++j) {
                int row = row0 + wave * 32 + m * 16 + rg + j;
                if (row < M) {
                    float val = acc[m][n][j];
                    if (EPI == 0) {
                        Cf[(size_t)row * N + col] = val;
                    } else if (EPI == 1) {
                        val = fmaxf(val + bias[col], 0.f);
                        Cb[(size_t)row * N + col] = __float2bfloat16(val);
                    } else {
                        val += bias[col] + Cf[(size_t)row * N + col];
                        Cf[(size_t)row * N + col] = val;
                        Cb[(size_t)row * N + col] = __float2bfloat16(val);
                    }
                }
            }
        }
    }
}

// ---------------- attention: wave per dst node, 2-pass segment softmax, bf16 out ----------------
__global__ __launch_bounds__(256) void attn_kernel(const float* __restrict__ qk,
        const float* __restrict__ v, const int* __restrict__ off,
        const int* __restrict__ csr_src, __hip_bfloat16* __restrict__ aggb, int n) {
    int wave = threadIdx.x >> 6;
    int lane = threadIdx.x & 63;
    int i = blockIdx.x * 4 + wave;
    if (i >= n) return;
    int d0 = lane * 2;
    float2 k2 = *reinterpret_cast<const float2*>(qk + (size_t)i * 256 + 128 + d0);
    int e0 = off[i], e1 = off[i + 1];
    float m = -INFINITY;
    for (int e = e0; e < e1; ++e) {
        int s = csr_src[e];
        float2 q2 = *reinterpret_cast<const float2*>(qk + (size_t)s * 256 + d0);
        float part = q2.x * k2.x + q2.y * k2.y;
        part += __shfl_xor(part, 1);
        part += __shfl_xor(part, 2);
        part += __shfl_xor(part, 4);
        m = fmaxf(m, part * SCALE);
    }
    float ssum = 0.f, ax = 0.f, ay = 0.f;
    for (int e = e0; e < e1; ++e) {
        int s = csr_src[e];
        float2 q2 = *reinterpret_cast<const float2*>(qk + (size_t)s * 256 + d0);
        float part = q2.x * k2.x + q2.y * k2.y;
        part += __shfl_xor(part, 1);
        part += __shfl_xor(part, 2);
        part += __shfl_xor(part, 4);
        float p = expf(part * SCALE - m);
        ssum += p;
        float2 v2 = *reinterpret_cast<const float2*>(v + (size_t)s * 128 + d0);
        ax += p * v2.x;
        ay += p * v2.y;
    }
    float inv = (e1 > e0) ? 1.f / ssum : 0.f;
    aggb[(size_t)i * 128 + d0] = __float2bfloat16(ax * inv);
    aggb[(size_t)i * 128 + d0 + 1] = __float2bfloat16(ay * inv);
}

// ---------------- pooling (deterministic, batch sorted) ----------------
__global__ void group_bounds_kernel(const int* __restrict__ batch, int n, int* __restrict__ gstart) {
    int g = threadIdx.x;
    if (g > NG) return;
    int lo = 0, hi = n;
    while (lo < hi) {
        int mid = (lo + hi) >> 1;
        if (batch[mid] < g) lo = mid + 1; else hi = mid;
    }
    gstart[g] = lo;
}

__global__ __launch_bounds__(256) void pool_kernel2(const float* __restrict__ h,
        const int* __restrict__ gstart, float* __restrict__ out) {
    int g = blockIdx.x;
    int s = gstart[g], e = gstart[g + 1];
    int c = threadIdx.x & 127;
    int half = threadIdx.x >> 7;
    float acc = 0.f;
    for (int r = s + half; r < e; r += 2)
        acc += h[(size_t)r * 128 + c];
    __shared__ float tmp[2][128];
    tmp[half][c] = acc;
    __syncthreads();
    if (half == 0) {
        float v = tmp[0][c] + tmp[1][c];
        float cntf = (float)(e - s);
        out[(size_t)g * 128 + c] = v / fmaxf(cntf, 1.f);
    }
}

extern "C" void kernel_launch(void* const* d_in, const int* in_sizes, int n_in,
                              void* d_out, int out_size, void* d_ws, size_t ws_size,
                              hipStream_t stream) {
    const float* x = (const float*)d_in[0];
    const int* ei = (const int*)d_in[1];
    const int* batch = (const int*)d_in[2];
    const float* W_embed = (const float*)d_in[3];
    const float* Wqk = (const float*)d_in[4];
    const float* Wv = (const float*)d_in[5];
    const float* Wout = (const float*)d_in[6];
    const float* b_out = (const float*)d_in[7];
    const float* W1 = (const float*)d_in[8];
    const float* b1 = (const float*)d_in[9];
    const float* W2 = (const float*)d_in[10];
    const float* b2 = (const float*)d_in[11];

    int Nn = in_sizes[2];
    int E = in_sizes[1] / 2;

    char* p = (char*)d_ws;
    auto alloc = [&](size_t bytes) {
        char* r = p;
        p += (bytes + 255) & ~(size_t)255;
        return r;
    };
    float* h32 = (float*)alloc((size_t)Nn * D * 4);
    float* qk = (float*)alloc((size_t)Nn * 2 * D * 4);          // also aliased by ff1b
    float* v = (float*)alloc((size_t)Nn * D * 4);
    __hip_bfloat16* hb = (__hip_bfloat16*)alloc((size_t)Nn * D * 2);
    __hip_bfloat16* aggb = (__hip_bfloat16*)alloc((size_t)Nn * D * 2);
    __hip_bfloat16* WqkT = (__hip_bfloat16*)alloc((size_t)NL * 2 * D * D * 2);
    __hip_bfloat16* WvT = (__hip_bfloat16*)alloc((size_t)NL * D * D * 2);
    __hip_bfloat16* WoutT = (__hip_bfloat16*)alloc((size_t)NL * D * D * 2);
    __hip_bfloat16* W1T = (__hip_bfloat16*)alloc((size_t)NL * D * DFF * 2);
    __hip_bfloat16* W2T = (__hip_bfloat16*)alloc((size_t)NL * DFF * D * 2);
    int* csr_src = (int*)alloc((size_t)E * 4);
    int* cnt = (int*)alloc((size_t)Nn * 4);
    int* incl = (int*)alloc((size_t)Nn * 4);
    int* off = (int*)alloc(((size_t)Nn + 1) * 4);
    int* cur = (int*)alloc((size_t)Nn * 4);
    int* partials = (int*)alloc(1024 * 4);
    int* gstart = (int*)alloc((NG + 1) * 4);

    __hip_bfloat16* ff1b = (__hip_bfloat16*)qk;   // alias: qk dead once ffn starts

    const int* e_src = ei;
    const int* e_dst = ei + E;

    // CSR build (by dst)
    hipMemsetAsync(cnt, 0, (size_t)Nn * 4, stream);
    count_kernel<<<(E + 255) / 256, 256, 0, stream>>>(e_dst, cnt, E);
    int nsb = (Nn + 1023) / 1024;
    scan_block_kernel<<<nsb, 1024, 0, stream>>>(cnt, incl, partials, Nn);
    scan_partials_kernel<<<1, 64, 0, stream>>>(partials, nsb);
    finalize_off_kernel<<<(Nn + 255) / 256, 256, 0, stream>>>(cnt, incl, partials, off, cur, Nn, E);
    scatter_kernel<<<(E + 255) / 256, 256, 0, stream>>>(e_src, e_dst, cur, csr_src, E);

    // weight transposes (f32 -> bf16, N x K layout)
    transpose_cvt_kernel<<<dim3((2 * D * D + 255) / 256, NL), 256, 0, stream>>>(Wqk, WqkT, D, 2 * D);
    transpose_cvt_kernel<<<dim3((D * D + 255) / 256, NL), 256, 0, stream>>>(Wv, WvT, D, D);
    transpose_cvt_kernel<<<dim3((D * D + 255) / 256, NL), 256, 0, stream>>>(Wout, WoutT, D, D);
    transpose_cvt_kernel<<<dim3((D * DFF + 255) / 256, NL), 256, 0, stream>>>(W1, W1T, D, DFF);
    transpose_cvt_kernel<<<dim3((DFF * D + 255) / 256, NL), 256, 0, stream>>>(W2, W2T, DFF, D);

    // embed: h32 = x @ W_embed (fp32, K=100), then bf16 shadow
    int gmb64 = (Nn + 63) / 64;
    gemm64<false, false><<<dim3(gmb64, D / 64), 256, 0, stream>>>(x, W_embed, nullptr, h32, Nn, D, FIN);
    cvt_kernel<<<(Nn * D / 4 + 255) / 256, 256, 0, stream>>>(h32, hb, Nn * D / 4);

    int gmb = (Nn + 127) / 128;
    for (int l = 0; l < NL; ++l) {
        gemm_mfma<0><<<dim3(gmb, 2 * D / 64), 256, 0, stream>>>(
            hb, WqkT + (size_t)l * 2 * D * D, nullptr, qk, nullptr, Nn, 2 * D, D);
        gemm_mfma<0><<<dim3(gmb, D / 64), 256, 0, stream>>>(
            hb, WvT + (size_t)l * D * D, nullptr, v, nullptr, Nn, D, D);
        attn_kernel<<<(Nn + 3) / 4, 256, 0, stream>>>(qk, v, off, csr_src, aggb, Nn);
        gemm_mfma<2><<<dim3(gmb, D / 64), 256, 0, stream>>>(
            aggb, WoutT + (size_t)l * D * D, b_out + (size_t)l * D, h32, hb, Nn, D, D);
        gemm_mfma<1><<<dim3(gmb, DFF / 64), 256, 0, stream>>>(
            hb, W1T + (size_t)l * D * DFF, b1 + (size_t)l * DFF, nullptr, ff1b, Nn, DFF, D);
        gemm_mfma<2><<<dim3(gmb, D / 64), 256, 0, stream>>>(
            ff1b, W2T + (size_t)l * DFF * D, b2 + (size_t)l * D, h32, hb, Nn, D, DFF);
    }

    group_bounds_kernel<<<1, 128, 0, stream>>>(batch, Nn, gstart);
    pool_kernel2<<<NG, 256, 0, stream>>>(h32, gstart, (float*)d_out);
}

// Round 3
// 949.940 us; speedup vs baseline: 3.5227x; 1.4917x over previous
//
#include <hip/hip_runtime.h>
#include <hip/hip_bf16.h>
#include <math.h>

#define D 128
#define NH 8
#define DFF 512
#define NG 64
#define NL 4
#define FIN 100
#define SCALE 0.25f

typedef __attribute__((ext_vector_type(8))) short short8;
typedef __attribute__((ext_vector_type(4))) float f32x4;

// ---------------- CSR build ----------------
__global__ void count_kernel(const int* __restrict__ dst, int* __restrict__ cnt, int E) {
    int e = blockIdx.x * 256 + threadIdx.x;
    if (e < E) atomicAdd(&cnt[dst[e]], 1);
}

__global__ __launch_bounds__(1024) void scan_block_kernel(const int* __restrict__ cnt,
        int* __restrict__ incl, int* __restrict__ partials, int n) {
    __shared__ int s[1024];
    int tid = threadIdx.x;
    int gid = blockIdx.x * 1024 + tid;
    int val = (gid < n) ? cnt[gid] : 0;
    s[tid] = val;
    __syncthreads();
    for (int o = 1; o < 1024; o <<= 1) {
        int t = (tid >= o) ? s[tid - o] : 0;
        __syncthreads();
        s[tid] += t;
        __syncthreads();
    }
    if (gid < n) incl[gid] = s[tid];
    if (tid == 1023) partials[blockIdx.x] = s[1023];
}

__global__ void scan_partials_kernel(int* __restrict__ partials, int nb) {
    if (threadIdx.x == 0 && blockIdx.x == 0) {
        int run = 0;
        for (int i = 0; i < nb; ++i) { int t = partials[i]; partials[i] = run; run += t; }
    }
}

__global__ void finalize_off_kernel(const int* __restrict__ cnt, const int* __restrict__ incl,
        const int* __restrict__ partials, int* __restrict__ off, int* __restrict__ cur,
        int n, int E) {
    int gid = blockIdx.x * 256 + threadIdx.x;
    if (gid < n) {
        int v = incl[gid] - cnt[gid] + partials[gid >> 10];
        off[gid] = v;
        cur[gid] = v;
    }
    if (gid == 0) off[n] = E;
}

__global__ void scatter_kernel(const int* __restrict__ src, const int* __restrict__ dst,
        int* __restrict__ cur, int* __restrict__ csr_src, int E) {
    int e = blockIdx.x * 256 + threadIdx.x;
    if (e < E) {
        int p = atomicAdd(&cur[dst[e]], 1);
        csr_src[p] = src[e];
    }
}

// ---------------- weight transpose + bf16 convert: W[K][N] -> Bt[N][K], per layer ----------------
__global__ void transpose_cvt_kernel(const float* __restrict__ W, __hip_bfloat16* __restrict__ Bt,
        int K, int N) {
    int l = blockIdx.y;
    const float* w = W + (size_t)l * K * N;
    __hip_bfloat16* bt = Bt + (size_t)l * K * N;
    int idx = blockIdx.x * 256 + threadIdx.x;
    if (idx >= K * N) return;
    int n = idx / K, k = idx - n * K;
    bt[idx] = __float2bfloat16(w[(size_t)k * N + n]);
}

// ---------------- f32 -> bf16 vector convert ----------------
__global__ void cvt_kernel(const float* __restrict__ in, __hip_bfloat16* __restrict__ out, int n4) {
    int i = blockIdx.x * 256 + threadIdx.x;
    if (i < n4) {
        float4 v = reinterpret_cast<const float4*>(in)[i];
        out[i * 4 + 0] = __float2bfloat16(v.x);
        out[i * 4 + 1] = __float2bfloat16(v.y);
        out[i * 4 + 2] = __float2bfloat16(v.z);
        out[i * 4 + 3] = __float2bfloat16(v.w);
    }
}

// ---------------- fp32 tiled GEMM (embed only, K=100) ----------------
template<bool BIAS, bool RES>
__global__ __launch_bounds__(256) void gemm64(const float* __restrict__ A,
        const float* __restrict__ B, const float* __restrict__ bias,
        float* __restrict__ C, int M, int N, int K) {
    __shared__ float As[64][33];
    __shared__ float Bs[32][65];
    int t = threadIdx.x;
    int row0 = blockIdx.x * 64, col0 = blockIdx.y * 64;
    int tx = t & 15, ty = t >> 4;
    float acc[4][4] = {};
    for (int k0 = 0; k0 < K; k0 += 32) {
#pragma unroll
        for (int i = 0; i < 8; ++i) {
            int idx = t + i * 256;
            int r = idx >> 5, kk = idx & 31;
            int gr = row0 + r, gk = k0 + kk;
            As[r][kk] = (gr < M && gk < K) ? A[(size_t)gr * K + gk] : 0.f;
        }
#pragma unroll
        for (int i = 0; i < 8; ++i) {
            int idx = t + i * 256;
            int kk = idx >> 6, c = idx & 63;
            int gk = k0 + kk;
            Bs[kk][c] = (gk < K) ? B[(size_t)gk * N + col0 + c] : 0.f;
        }
        __syncthreads();
#pragma unroll
        for (int kk = 0; kk < 32; ++kk) {
            float b0 = Bs[kk][tx * 4 + 0];
            float b1v = Bs[kk][tx * 4 + 1];
            float b2v = Bs[kk][tx * 4 + 2];
            float b3v = Bs[kk][tx * 4 + 3];
#pragma unroll
            for (int r = 0; r < 4; ++r) {
                float a = As[ty * 4 + r][kk];
                acc[r][0] += a * b0;
                acc[r][1] += a * b1v;
                acc[r][2] += a * b2v;
                acc[r][3] += a * b3v;
            }
        }
        __syncthreads();
    }
#pragma unroll
    for (int r = 0; r < 4; ++r) {
        int gr = row0 + ty * 4 + r;
        if (gr < M) {
#pragma unroll
            for (int i = 0; i < 4; ++i) {
                int gc = col0 + tx * 4 + i;
                float v = acc[r][i];
                if (BIAS) v += bias[gc];
                if (RES) v += C[(size_t)gr * N + gc];
                C[(size_t)gr * N + gc] = v;
            }
        }
    }
}

// ---------------- bf16 MFMA GEMM: ops(A[M,K] @ Bt[N,K]^T), tile 128x64, BK=64 ----------------
// EPI 0: Cb = bf16(acc)                             (bf16 out, no bias)
// EPI 1: Cb = bf16(relu(acc + bias))                (bf16 out)
// EPI 2: v = Cf + acc + bias; Cf = v; Cb = bf16(v)  (residual, dual write)
template<int EPI>
__global__ __launch_bounds__(256) void gemm_mfma(
        const __hip_bfloat16* __restrict__ A, const __hip_bfloat16* __restrict__ Bt,
        const float* __restrict__ bias,
        float* __restrict__ Cf, __hip_bfloat16* __restrict__ Cb,
        int M, int N, int K) {
    __shared__ __align__(16) unsigned short As[128][64];
    __shared__ __align__(16) unsigned short Bs[64][64];
    int t = threadIdx.x;
    int wave = t >> 6, lane = t & 63;
    int row0 = blockIdx.x * 128, col0 = blockIdx.y * 64;
    f32x4 acc[2][4] = {};

    int sr = t >> 3;       // staging row within 32-row slab
    int sc = t & 7;        // staging 16B chunk 0..7

    for (int k0 = 0; k0 < K; k0 += 64) {
#pragma unroll
        for (int i = 0; i < 4; ++i) {
            int r = i * 32 + sr;
            int gr = row0 + r;
            if (gr >= M) gr = M - 1;
            *reinterpret_cast<short8*>(&As[r][(sc ^ (r & 7)) << 3]) =
                *reinterpret_cast<const short8*>(&A[(size_t)gr * K + k0 + (sc << 3)]);
        }
#pragma unroll
        for (int i = 0; i < 2; ++i) {
            int r = i * 32 + sr;
            *reinterpret_cast<short8*>(&Bs[r][(sc ^ (r & 7)) << 3]) =
                *reinterpret_cast<const short8*>(&Bt[(size_t)(col0 + r) * K + k0 + (sc << 3)]);
        }
        __syncthreads();
#pragma unroll
        for (int kk = 0; kk < 64; kk += 32) {
            int lr = lane & 15;
            int kc = (kk >> 3) + (lane >> 4);   // k-chunk index
            short8 a[2], b[4];
#pragma unroll
            for (int m = 0; m < 2; ++m) {
                int r = wave * 32 + m * 16 + lr;
                a[m] = *reinterpret_cast<const short8*>(&As[r][(kc ^ (r & 7)) << 3]);
            }
#pragma unroll
            for (int n = 0; n < 4; ++n) {
                int r = n * 16 + lr;
                b[n] = *reinterpret_cast<const short8*>(&Bs[r][(kc ^ (r & 7)) << 3]);
            }
#pragma unroll
            for (int m = 0; m < 2; ++m)
#pragma unroll
                for (int n = 0; n < 4; ++n)
                    acc[m][n] = __builtin_amdgcn_mfma_f32_16x16x32_bf16(a[m], b[n], acc[m][n], 0, 0, 0);
        }
        __syncthreads();
    }

    int lr = lane & 15, rg = (lane >> 4) * 4;
#pragma unroll
    for (int m = 0; m < 2; ++m) {
#pragma unroll
        for (int n = 0; n < 4; ++n) {
            int col = col0 + n * 16 + lr;
#pragma unroll
            for (int j = 0; j < 4; ++j) {
                int row = row0 + wave * 32 + m * 16 + rg + j;
                if (row < M) {
                    float val = acc[m][n][j];
                    if (EPI == 0) {
                        Cb[(size_t)row * N + col] = __float2bfloat16(val);
                    } else if (EPI == 1) {
                        val = fmaxf(val + bias[col], 0.f);
                        Cb[(size_t)row * N + col] = __float2bfloat16(val);
                    } else {
                        val += bias[col] + Cf[(size_t)row * N + col];
                        Cf[(size_t)row * N + col] = val;
                        Cb[(size_t)row * N + col] = __float2bfloat16(val);
                    }
                }
            }
        }
    }
}

// ---------------- attention: wave/dst, ONE-PASS online softmax, bf16 in/out ----------------
__global__ __launch_bounds__(256) void attn_kernel(const __hip_bfloat16* __restrict__ qkb,
        const __hip_bfloat16* __restrict__ vb, const int* __restrict__ off,
        const int* __restrict__ csr_src, __hip_bfloat16* __restrict__ aggb, int n) {
    int wave = threadIdx.x >> 6;
    int lane = threadIdx.x & 63;
    int i = blockIdx.x * 4 + wave;
    if (i >= n) return;
    const unsigned* qk32 = reinterpret_cast<const unsigned*>(qkb);
    const unsigned* v32 = reinterpret_cast<const unsigned*>(vb);
    // k row i, dims (2*lane, 2*lane+1): dword index i*128 + 64 + lane
    unsigned ku = qk32[(size_t)i * 128 + 64 + lane];
    float kx = __uint_as_float(ku << 16);
    float ky = __uint_as_float(ku & 0xffff0000u);
    int e0 = off[i], e1 = off[i + 1];
    float m = -INFINITY, ssum = 0.f, ax = 0.f, ay = 0.f;
    int e = e0;
    for (; e + 2 <= e1; e += 2) {
        int s0 = csr_src[e], s1 = csr_src[e + 1];
        unsigned q0 = qk32[(size_t)s0 * 128 + lane];
        unsigned q1 = qk32[(size_t)s1 * 128 + lane];
        unsigned w0 = v32[(size_t)s0 * 64 + lane];
        unsigned w1 = v32[(size_t)s1 * 64 + lane];
        float l0 = __uint_as_float(q0 << 16) * kx + __uint_as_float(q0 & 0xffff0000u) * ky;
        float l1 = __uint_as_float(q1 << 16) * kx + __uint_as_float(q1 & 0xffff0000u) * ky;
        l0 += __shfl_xor(l0, 1); l0 += __shfl_xor(l0, 2); l0 += __shfl_xor(l0, 4);
        l1 += __shfl_xor(l1, 1); l1 += __shfl_xor(l1, 2); l1 += __shfl_xor(l1, 4);
        l0 *= SCALE; l1 *= SCALE;
        float mn = fmaxf(m, l0);
        float corr = __expf(m - mn);
        float pe = __expf(l0 - mn);
        ssum = ssum * corr + pe;
        ax = ax * corr + pe * __uint_as_float(w0 << 16);
        ay = ay * corr + pe * __uint_as_float(w0 & 0xffff0000u);
        m = mn;
        mn = fmaxf(m, l1);
        corr = __expf(m - mn);
        pe = __expf(l1 - mn);
        ssum = ssum * corr + pe;
        ax = ax * corr + pe * __uint_as_float(w1 << 16);
        ay = ay * corr + pe * __uint_as_float(w1 & 0xffff0000u);
        m = mn;
    }
    if (e < e1) {
        int s0 = csr_src[e];
        unsigned q0 = qk32[(size_t)s0 * 128 + lane];
        unsigned w0 = v32[(size_t)s0 * 64 + lane];
        float l0 = __uint_as_float(q0 << 16) * kx + __uint_as_float(q0 & 0xffff0000u) * ky;
        l0 += __shfl_xor(l0, 1); l0 += __shfl_xor(l0, 2); l0 += __shfl_xor(l0, 4);
        l0 *= SCALE;
        float mn = fmaxf(m, l0);
        float corr = __expf(m - mn);
        float pe = __expf(l0 - mn);
        ssum = ssum * corr + pe;
        ax = ax * corr + pe * __uint_as_float(w0 << 16);
        ay = ay * corr + pe * __uint_as_float(w0 & 0xffff0000u);
    }
    float inv = (ssum > 0.f) ? 1.f / ssum : 0.f;
    __hip_bfloat162 o;
    o.x = __float2bfloat16(ax * inv);
    o.y = __float2bfloat16(ay * inv);
    *reinterpret_cast<__hip_bfloat162*>(aggb + (size_t)i * 128 + lane * 2) = o;
}

// ---------------- pooling (deterministic, batch sorted) ----------------
__global__ void group_bounds_kernel(const int* __restrict__ batch, int n, int* __restrict__ gstart) {
    int g = threadIdx.x;
    if (g > NG) return;
    int lo = 0, hi = n;
    while (lo < hi) {
        int mid = (lo + hi) >> 1;
        if (batch[mid] < g) lo = mid + 1; else hi = mid;
    }
    gstart[g] = lo;
}

__global__ __launch_bounds__(256) void pool_kernel2(const float* __restrict__ h,
        const int* __restrict__ gstart, float* __restrict__ out) {
    int g = blockIdx.x;
    int s = gstart[g], e = gstart[g + 1];
    int c = threadIdx.x & 127;
    int half = threadIdx.x >> 7;
    float acc = 0.f;
    for (int r = s + half; r < e; r += 2)
        acc += h[(size_t)r * 128 + c];
    __shared__ float tmp[2][128];
    tmp[half][c] = acc;
    __syncthreads();
    if (half == 0) {
        float v = tmp[0][c] + tmp[1][c];
        float cntf = (float)(e - s);
        out[(size_t)g * 128 + c] = v / fmaxf(cntf, 1.f);
    }
}

extern "C" void kernel_launch(void* const* d_in, const int* in_sizes, int n_in,
                              void* d_out, int out_size, void* d_ws, size_t ws_size,
                              hipStream_t stream) {
    const float* x = (const float*)d_in[0];
    const int* ei = (const int*)d_in[1];
    const int* batch = (const int*)d_in[2];
    const float* W_embed = (const float*)d_in[3];
    const float* Wqk = (const float*)d_in[4];
    const float* Wv = (const float*)d_in[5];
    const float* Wout = (const float*)d_in[6];
    const float* b_out = (const float*)d_in[7];
    const float* W1 = (const float*)d_in[8];
    const float* b1 = (const float*)d_in[9];
    const float* W2 = (const float*)d_in[10];
    const float* b2 = (const float*)d_in[11];

    int Nn = in_sizes[2];
    int E = in_sizes[1] / 2;

    char* p = (char*)d_ws;
    auto alloc = [&](size_t bytes) {
        char* r = p;
        p += (bytes + 255) & ~(size_t)255;
        return r;
    };
    float* h32 = (float*)alloc((size_t)Nn * D * 4);
    __hip_bfloat16* qkb = (__hip_bfloat16*)alloc((size_t)Nn * 2 * D * 2);
    __hip_bfloat16* vb = (__hip_bfloat16*)alloc((size_t)Nn * D * 2);
    __hip_bfloat16* hb = (__hip_bfloat16*)alloc((size_t)Nn * D * 2);
    __hip_bfloat16* aggb = (__hip_bfloat16*)alloc((size_t)Nn * D * 2);
    __hip_bfloat16* ff1b = (__hip_bfloat16*)alloc((size_t)Nn * DFF * 2);
    __hip_bfloat16* WqkT = (__hip_bfloat16*)alloc((size_t)NL * 2 * D * D * 2);
    __hip_bfloat16* WvT = (__hip_bfloat16*)alloc((size_t)NL * D * D * 2);
    __hip_bfloat16* WoutT = (__hip_bfloat16*)alloc((size_t)NL * D * D * 2);
    __hip_bfloat16* W1T = (__hip_bfloat16*)alloc((size_t)NL * D * DFF * 2);
    __hip_bfloat16* W2T = (__hip_bfloat16*)alloc((size_t)NL * DFF * D * 2);
    int* csr_src = (int*)alloc((size_t)E * 4);
    int* cnt = (int*)alloc((size_t)Nn * 4);
    int* incl = (int*)alloc((size_t)Nn * 4);
    int* off = (int*)alloc(((size_t)Nn + 1) * 4);
    int* cur = (int*)alloc((size_t)Nn * 4);
    int* partials = (int*)alloc(1024 * 4);
    int* gstart = (int*)alloc((NG + 1) * 4);

    const int* e_src = ei;
    const int* e_dst = ei + E;

    // CSR build (by dst)
    hipMemsetAsync(cnt, 0, (size_t)Nn * 4, stream);
    count_kernel<<<(E + 255) / 256, 256, 0, stream>>>(e_dst, cnt, E);
    int nsb = (Nn + 1023) / 1024;
    scan_block_kernel<<<nsb, 1024, 0, stream>>>(cnt, incl, partials, Nn);
    scan_partials_kernel<<<1, 64, 0, stream>>>(partials, nsb);
    finalize_off_kernel<<<(Nn + 255) / 256, 256, 0, stream>>>(cnt, incl, partials, off, cur, Nn, E);
    scatter_kernel<<<(E + 255) / 256, 256, 0, stream>>>(e_src, e_dst, cur, csr_src, E);

    // weight transposes (f32 -> bf16, N x K layout)
    transpose_cvt_kernel<<<dim3((2 * D * D + 255) / 256, NL), 256, 0, stream>>>(Wqk, WqkT, D, 2 * D);
    transpose_cvt_kernel<<<dim3((D * D + 255) / 256, NL), 256, 0, stream>>>(Wv, WvT, D, D);
    transpose_cvt_kernel<<<dim3((D * D + 255) / 256, NL), 256, 0, stream>>>(Wout, WoutT, D, D);
    transpose_cvt_kernel<<<dim3((D * DFF + 255) / 256, NL), 256, 0, stream>>>(W1, W1T, D, DFF);
    transpose_cvt_kernel<<<dim3((DFF * D + 255) / 256, NL), 256, 0, stream>>>(W2, W2T, DFF, D);

    // embed: h32 = x @ W_embed (fp32, K=100), then bf16 shadow
    int gmb64 = (Nn + 63) / 64;
    gemm64<false, false><<<dim3(gmb64, D / 64), 256, 0, stream>>>(x, W_embed, nullptr, h32, Nn, D, FIN);
    cvt_kernel<<<(Nn * D / 4 + 255) / 256, 256, 0, stream>>>(h32, hb, Nn * D / 4);

    int gmb = (Nn + 127) / 128;
    for (int l = 0; l < NL; ++l) {
        gemm_mfma<0><<<dim3(gmb, 2 * D / 64), 256, 0, stream>>>(
            hb, WqkT + (size_t)l * 2 * D * D, nullptr, nullptr, qkb, Nn, 2 * D, D);
        gemm_mfma<0><<<dim3(gmb, D / 64), 256, 0, stream>>>(
            hb, WvT + (size_t)l * D * D, nullptr, nullptr, vb, Nn, D, D);
        attn_kernel<<<(Nn + 3) / 4, 256, 0, stream>>>(qkb, vb, off, csr_src, aggb, Nn);
        gemm_mfma<2><<<dim3(gmb, D / 64), 256, 0, stream>>>(
            aggb, WoutT + (size_t)l * D * D, b_out + (size_t)l * D, h32, hb, Nn, D, D);
        gemm_mfma<1><<<dim3(gmb, DFF / 64), 256, 0, stream>>>(
            hb, W1T + (size_t)l * D * DFF, b1 + (size_t)l * DFF, nullptr, ff1b, Nn, DFF, D);
        gemm_mfma<2><<<dim3(gmb, D / 64), 256, 0, stream>>>(
            ff1b, W2T + (size_t)l * DFF * D, b2 + (size_t)l * D, h32, hb, Nn, D, DFF);
    }

    group_bounds_kernel<<<1, 128, 0, stream>>>(batch, Nn, gstart);
    pool_kernel2<<<NG, 256, 0, stream>>>(h32, gstart, (float*)d_out);
}

// Round 4
// 765.849 us; speedup vs baseline: 4.3694x; 1.2404x over previous
//
#include <hip/hip_runtime.h>
#include <hip/hip_bf16.h>
#include <math.h>

#define D 128
#define NH 8
#define DFF 512
#define NG 64
#define NL 4
#define FIN 100
#define SCALE 0.25f
#define QKV 384

typedef __attribute__((ext_vector_type(8))) short short8;
typedef __attribute__((ext_vector_type(4))) float f32x4;

// ---------------- CSR build ----------------
__global__ void count_kernel(const int* __restrict__ dst, int* __restrict__ cnt, int E) {
    int e = blockIdx.x * 256 + threadIdx.x;
    if (e < E) atomicAdd(&cnt[dst[e]], 1);
}

__global__ __launch_bounds__(1024) void scan_block_kernel(const int* __restrict__ cnt,
        int* __restrict__ incl, int* __restrict__ partials, int n) {
    __shared__ int s[1024];
    int tid = threadIdx.x;
    int gid = blockIdx.x * 1024 + tid;
    int val = (gid < n) ? cnt[gid] : 0;
    s[tid] = val;
    __syncthreads();
    for (int o = 1; o < 1024; o <<= 1) {
        int t = (tid >= o) ? s[tid - o] : 0;
        __syncthreads();
        s[tid] += t;
        __syncthreads();
    }
    if (gid < n) incl[gid] = s[tid];
    if (tid == 1023) partials[blockIdx.x] = s[1023];
}

__global__ void scan_partials_kernel(int* __restrict__ partials, int nb) {
    if (threadIdx.x == 0 && blockIdx.x == 0) {
        int run = 0;
        for (int i = 0; i < nb; ++i) { int t = partials[i]; partials[i] = run; run += t; }
    }
}

__global__ void finalize_off_kernel(const int* __restrict__ cnt, const int* __restrict__ incl,
        const int* __restrict__ partials, int* __restrict__ off, int* __restrict__ cur,
        int n, int E) {
    int gid = blockIdx.x * 256 + threadIdx.x;
    if (gid < n) {
        int v = incl[gid] - cnt[gid] + partials[gid >> 10];
        off[gid] = v;
        cur[gid] = v;
    }
    if (gid == 0) off[n] = E;
}

__global__ void scatter_kernel(const int* __restrict__ src, const int* __restrict__ dst,
        int* __restrict__ cur, int* __restrict__ csr_src, int E) {
    int e = blockIdx.x * 256 + threadIdx.x;
    if (e < E) {
        int p = atomicAdd(&cur[dst[e]], 1);
        csr_src[p] = src[e];
    }
}

// ---- weight transpose + bf16 convert: W[K][N] -> Bt[n][k] (out layer stride ldl) ----
__global__ void transpose_cvt_kernel(const float* __restrict__ W, __hip_bfloat16* __restrict__ Bt,
        int K, int N, int ldl) {
    int l = blockIdx.y;
    const float* w = W + (size_t)l * K * N;
    __hip_bfloat16* bt = Bt + (size_t)l * ldl;
    int idx = blockIdx.x * 256 + threadIdx.x;
    if (idx >= K * N) return;
    int n = idx / K, k = idx - n * K;
    bt[(size_t)n * K + k] = __float2bfloat16(w[(size_t)k * N + n]);
}

// ---- embed input pad+cvt: x[N][100] f32 -> xb[N][128] bf16 (zero-padded) ----
__global__ void pad_cvt_x_kernel(const float* __restrict__ x, __hip_bfloat16* __restrict__ xb, int n) {
    int idx = blockIdx.x * 256 + threadIdx.x;
    if (idx >= n * 128) return;
    int r = idx >> 7, c = idx & 127;
    xb[idx] = (c < FIN) ? __float2bfloat16(x[(size_t)r * FIN + c]) : __float2bfloat16(0.f);
}

// ---- W_embed[100][128] -> WembT[128][128] bf16 (k zero-padded) ----
__global__ void wembT_kernel(const float* __restrict__ W, __hip_bfloat16* __restrict__ Bt) {
    int idx = blockIdx.x * 256 + threadIdx.x;
    if (idx >= 128 * 128) return;
    int n = idx >> 7, k = idx & 127;
    Bt[idx] = (k < FIN) ? __float2bfloat16(W[(size_t)k * 128 + n]) : __float2bfloat16(0.f);
}

// ---------------- bf16 MFMA GEMM: A[M,K] @ Bt[N,K]^T, tile 128x64, BK=64 ----------------
// EPI 0: Cb = bf16(acc)
// EPI 1: Cb = bf16(relu(acc + bias))
// EPI 2: v = Cf + acc + bias; Cf = v; Cb = bf16(v)   (residual, dual write)
// EPI 3: Cf = acc; Cb = bf16(acc)                    (dual write, no bias)
template<int EPI>
__global__ __launch_bounds__(256) void gemm_mfma(
        const __hip_bfloat16* __restrict__ A, const __hip_bfloat16* __restrict__ Bt,
        const float* __restrict__ bias,
        float* __restrict__ Cf, __hip_bfloat16* __restrict__ Cb,
        int M, int N, int K) {
    __shared__ __align__(16) unsigned short As[128][64];
    __shared__ __align__(16) unsigned short Bs[64][64];
    int t = threadIdx.x;
    int wave = t >> 6, lane = t & 63;
    int row0 = blockIdx.x * 128, col0 = blockIdx.y * 64;
    f32x4 acc[2][4] = {};

    int sr = t >> 3;
    int sc = t & 7;

    for (int k0 = 0; k0 < K; k0 += 64) {
#pragma unroll
        for (int i = 0; i < 4; ++i) {
            int r = i * 32 + sr;
            int gr = row0 + r;
            if (gr >= M) gr = M - 1;
            *reinterpret_cast<short8*>(&As[r][(sc ^ (r & 7)) << 3]) =
                *reinterpret_cast<const short8*>(&A[(size_t)gr * K + k0 + (sc << 3)]);
        }
#pragma unroll
        for (int i = 0; i < 2; ++i) {
            int r = i * 32 + sr;
            *reinterpret_cast<short8*>(&Bs[r][(sc ^ (r & 7)) << 3]) =
                *reinterpret_cast<const short8*>(&Bt[(size_t)(col0 + r) * K + k0 + (sc << 3)]);
        }
        __syncthreads();
#pragma unroll
        for (int kk = 0; kk < 64; kk += 32) {
            int lr = lane & 15;
            int kc = (kk >> 3) + (lane >> 4);
            short8 a[2], b[4];
#pragma unroll
            for (int m = 0; m < 2; ++m) {
                int r = wave * 32 + m * 16 + lr;
                a[m] = *reinterpret_cast<const short8*>(&As[r][(kc ^ (r & 7)) << 3]);
            }
#pragma unroll
            for (int n = 0; n < 4; ++n) {
                int r = n * 16 + lr;
                b[n] = *reinterpret_cast<const short8*>(&Bs[r][(kc ^ (r & 7)) << 3]);
            }
#pragma unroll
            for (int m = 0; m < 2; ++m)
#pragma unroll
                for (int n = 0; n < 4; ++n)
                    acc[m][n] = __builtin_amdgcn_mfma_f32_16x16x32_bf16(a[m], b[n], acc[m][n], 0, 0, 0);
        }
        __syncthreads();
    }

    int lr = lane & 15, rg = (lane >> 4) * 4;
#pragma unroll
    for (int m = 0; m < 2; ++m) {
#pragma unroll
        for (int n = 0; n < 4; ++n) {
            int col = col0 + n * 16 + lr;
#pragma unroll
            for (int j = 0; j < 4; ++j) {
                int row = row0 + wave * 32 + m * 16 + rg + j;
                if (row < M) {
                    float val = acc[m][n][j];
                    if (EPI == 0) {
                        Cb[(size_t)row * N + col] = __float2bfloat16(val);
                    } else if (EPI == 1) {
                        val = fmaxf(val + bias[col], 0.f);
                        Cb[(size_t)row * N + col] = __float2bfloat16(val);
                    } else if (EPI == 2) {
                        val += bias[col] + Cf[(size_t)row * N + col];
                        Cf[(size_t)row * N + col] = val;
                        Cb[(size_t)row * N + col] = __float2bfloat16(val);
                    } else {
                        Cf[(size_t)row * N + col] = val;
                        Cb[(size_t)row * N + col] = __float2bfloat16(val);
                    }
                }
            }
        }
    }
}

// ------- attention: wave/dst, 4-edge blocked online softmax, fused qkv rows -------
// qkv row (bf16): [0,128)=q, [128,256)=k, [256,384)=v ; as dwords: stride 192
__global__ __launch_bounds__(256) void attn_kernel(const __hip_bfloat16* __restrict__ qkvb,
        const int* __restrict__ off, const int* __restrict__ csr_src,
        __hip_bfloat16* __restrict__ aggb, int n) {
    int wave = threadIdx.x >> 6;
    int lane = threadIdx.x & 63;
    int i = blockIdx.x * 4 + wave;
    if (i >= n) return;
    const unsigned* qv = reinterpret_cast<const unsigned*>(qkvb);
    unsigned ku = qv[(size_t)i * 192 + 64 + lane];
    float kx = __uint_as_float(ku << 16);
    float ky = __uint_as_float(ku & 0xffff0000u);
    int e0 = off[i], e1 = off[i + 1];
    float m = -INFINITY, ssum = 0.f, ax = 0.f, ay = 0.f;
    int e = e0;
    for (; e + 4 <= e1; e += 4) {
        int s0 = csr_src[e], s1 = csr_src[e + 1], s2 = csr_src[e + 2], s3 = csr_src[e + 3];
        unsigned q0 = qv[(size_t)s0 * 192 + lane];
        unsigned q1 = qv[(size_t)s1 * 192 + lane];
        unsigned q2 = qv[(size_t)s2 * 192 + lane];
        unsigned q3 = qv[(size_t)s3 * 192 + lane];
        unsigned w0 = qv[(size_t)s0 * 192 + 128 + lane];
        unsigned w1 = qv[(size_t)s1 * 192 + 128 + lane];
        unsigned w2 = qv[(size_t)s2 * 192 + 128 + lane];
        unsigned w3 = qv[(size_t)s3 * 192 + 128 + lane];
        float l0 = __uint_as_float(q0 << 16) * kx + __uint_as_float(q0 & 0xffff0000u) * ky;
        float l1 = __uint_as_float(q1 << 16) * kx + __uint_as_float(q1 & 0xffff0000u) * ky;
        float l2 = __uint_as_float(q2 << 16) * kx + __uint_as_float(q2 & 0xffff0000u) * ky;
        float l3 = __uint_as_float(q3 << 16) * kx + __uint_as_float(q3 & 0xffff0000u) * ky;
        l0 += __shfl_xor(l0, 1); l1 += __shfl_xor(l1, 1); l2 += __shfl_xor(l2, 1); l3 += __shfl_xor(l3, 1);
        l0 += __shfl_xor(l0, 2); l1 += __shfl_xor(l1, 2); l2 += __shfl_xor(l2, 2); l3 += __shfl_xor(l3, 2);
        l0 += __shfl_xor(l0, 4); l1 += __shfl_xor(l1, 4); l2 += __shfl_xor(l2, 4); l3 += __shfl_xor(l3, 4);
        l0 *= SCALE; l1 *= SCALE; l2 *= SCALE; l3 *= SCALE;
        float mx = fmaxf(fmaxf(l0, l1), fmaxf(l2, l3));
        float mn = fmaxf(m, mx);
        float corr = __expf(m - mn);
        float p0 = __expf(l0 - mn);
        float p1 = __expf(l1 - mn);
        float p2 = __expf(l2 - mn);
        float p3 = __expf(l3 - mn);
        ssum = ssum * corr + ((p0 + p1) + (p2 + p3));
        ax = ax * corr + p0 * __uint_as_float(w0 << 16) + p1 * __uint_as_float(w1 << 16)
                       + p2 * __uint_as_float(w2 << 16) + p3 * __uint_as_float(w3 << 16);
        ay = ay * corr + p0 * __uint_as_float(w0 & 0xffff0000u) + p1 * __uint_as_float(w1 & 0xffff0000u)
                       + p2 * __uint_as_float(w2 & 0xffff0000u) + p3 * __uint_as_float(w3 & 0xffff0000u);
        m = mn;
    }
    for (; e < e1; ++e) {
        int s0 = csr_src[e];
        unsigned q0 = qv[(size_t)s0 * 192 + lane];
        unsigned w0 = qv[(size_t)s0 * 192 + 128 + lane];
        float l0 = __uint_as_float(q0 << 16) * kx + __uint_as_float(q0 & 0xffff0000u) * ky;
        l0 += __shfl_xor(l0, 1); l0 += __shfl_xor(l0, 2); l0 += __shfl_xor(l0, 4);
        l0 *= SCALE;
        float mn = fmaxf(m, l0);
        float corr = __expf(m - mn);
        float pe = __expf(l0 - mn);
        ssum = ssum * corr + pe;
        ax = ax * corr + pe * __uint_as_float(w0 << 16);
        ay = ay * corr + pe * __uint_as_float(w0 & 0xffff0000u);
        m = mn;
    }
    float inv = (ssum > 0.f) ? 1.f / ssum : 0.f;
    __hip_bfloat162 o;
    o.x = __float2bfloat16(ax * inv);
    o.y = __float2bfloat16(ay * inv);
    *reinterpret_cast<__hip_bfloat162*>(aggb + (size_t)i * 128 + lane * 2) = o;
}

// ---------------- pooling (deterministic two-stage, batch sorted) ----------------
__global__ void group_bounds_kernel(const int* __restrict__ batch, int n, int* __restrict__ gstart) {
    int g = threadIdx.x;
    if (g > NG) return;
    int lo = 0, hi = n;
    while (lo < hi) {
        int mid = (lo + hi) >> 1;
        if (batch[mid] < g) lo = mid + 1; else hi = mid;
    }
    gstart[g] = lo;
}

__global__ __launch_bounds__(256) void pool_stage1(const float* __restrict__ h,
        const int* __restrict__ gstart, float* __restrict__ pws) {
    int g = blockIdx.x, sub = blockIdx.y;
    int s = gstart[g], e = gstart[g + 1];
    int c = threadIdx.x & 127;
    int half = threadIdx.x >> 7;
    float acc = 0.f;
    for (int r = s + sub * 2 + half; r < e; r += 16)
        acc += h[(size_t)r * 128 + c];
    __shared__ float tmp[2][128];
    tmp[half][c] = acc;
    __syncthreads();
    if (half == 0)
        pws[((size_t)g * 8 + sub) * 128 + c] = tmp[0][c] + tmp[1][c];
}

__global__ void pool_stage2(const float* __restrict__ pws, const int* __restrict__ gstart,
        float* __restrict__ out) {
    int g = blockIdx.x, c = threadIdx.x;
    float s = 0.f;
#pragma unroll
    for (int i = 0; i < 8; ++i) s += pws[((size_t)g * 8 + i) * 128 + c];
    float cntf = (float)(gstart[g + 1] - gstart[g]);
    out[(size_t)g * 128 + c] = s / fmaxf(cntf, 1.f);
}

extern "C" void kernel_launch(void* const* d_in, const int* in_sizes, int n_in,
                              void* d_out, int out_size, void* d_ws, size_t ws_size,
                              hipStream_t stream) {
    const float* x = (const float*)d_in[0];
    const int* ei = (const int*)d_in[1];
    const int* batch = (const int*)d_in[2];
    const float* W_embed = (const float*)d_in[3];
    const float* Wqk = (const float*)d_in[4];
    const float* Wv = (const float*)d_in[5];
    const float* Wout = (const float*)d_in[6];
    const float* b_out = (const float*)d_in[7];
    const float* W1 = (const float*)d_in[8];
    const float* b1 = (const float*)d_in[9];
    const float* W2 = (const float*)d_in[10];
    const float* b2 = (const float*)d_in[11];

    int Nn = in_sizes[2];
    int E = in_sizes[1] / 2;

    char* p = (char*)d_ws;
    auto alloc = [&](size_t bytes) {
        char* r = p;
        p += (bytes + 255) & ~(size_t)255;
        return r;
    };
    float* h32 = (float*)alloc((size_t)Nn * D * 4);
    __hip_bfloat16* hb = (__hip_bfloat16*)alloc((size_t)Nn * D * 2);
    __hip_bfloat16* aggb = (__hip_bfloat16*)alloc((size_t)Nn * D * 2);
    // union region: qkvb [Nn][384] (qkv->attn) and ff1b [Nn][512] (ffn1->ffn2) are time-disjoint
    char* uni = alloc((size_t)Nn * DFF * 2);
    __hip_bfloat16* qkvb = (__hip_bfloat16*)uni;
    __hip_bfloat16* ff1b = (__hip_bfloat16*)uni;
    __hip_bfloat16* xb = (__hip_bfloat16*)alloc((size_t)Nn * D * 2);
    __hip_bfloat16* WembT = (__hip_bfloat16*)alloc((size_t)D * D * 2);
    __hip_bfloat16* WqkvT = (__hip_bfloat16*)alloc((size_t)NL * QKV * D * 2);
    __hip_bfloat16* WoutT = (__hip_bfloat16*)alloc((size_t)NL * D * D * 2);
    __hip_bfloat16* W1T = (__hip_bfloat16*)alloc((size_t)NL * D * DFF * 2);
    __hip_bfloat16* W2T = (__hip_bfloat16*)alloc((size_t)NL * DFF * D * 2);
    int* csr_src = (int*)alloc((size_t)E * 4);
    int* cnt = (int*)alloc((size_t)Nn * 4);
    int* incl = (int*)alloc((size_t)Nn * 4);
    int* off = (int*)alloc(((size_t)Nn + 1) * 4);
    int* cur = (int*)alloc((size_t)Nn * 4);
    int* partials = (int*)alloc(1024 * 4);
    int* gstart = (int*)alloc((NG + 1) * 4);
    float* pws = (float*)alloc((size_t)NG * 8 * 128 * 4);

    const int* e_src = ei;
    const int* e_dst = ei + E;

    // CSR build (by dst)
    hipMemsetAsync(cnt, 0, (size_t)Nn * 4, stream);
    count_kernel<<<(E + 255) / 256, 256, 0, stream>>>(e_dst, cnt, E);
    int nsb = (Nn + 1023) / 1024;
    scan_block_kernel<<<nsb, 1024, 0, stream>>>(cnt, incl, partials, Nn);
    scan_partials_kernel<<<1, 64, 0, stream>>>(partials, nsb);
    finalize_off_kernel<<<(Nn + 255) / 256, 256, 0, stream>>>(cnt, incl, partials, off, cur, Nn, E);
    scatter_kernel<<<(E + 255) / 256, 256, 0, stream>>>(e_src, e_dst, cur, csr_src, E);

    // weight prep
    transpose_cvt_kernel<<<dim3((2 * D * D + 255) / 256, NL), 256, 0, stream>>>(
        Wqk, WqkvT, D, 2 * D, QKV * D);
    transpose_cvt_kernel<<<dim3((D * D + 255) / 256, NL), 256, 0, stream>>>(
        Wv, WqkvT + (size_t)2 * D * D, D, D, QKV * D);
    transpose_cvt_kernel<<<dim3((D * D + 255) / 256, NL), 256, 0, stream>>>(
        Wout, WoutT, D, D, D * D);
    transpose_cvt_kernel<<<dim3((D * DFF + 255) / 256, NL), 256, 0, stream>>>(
        W1, W1T, D, DFF, D * DFF);
    transpose_cvt_kernel<<<dim3((DFF * D + 255) / 256, NL), 256, 0, stream>>>(
        W2, W2T, DFF, D, DFF * D);
    wembT_kernel<<<(128 * 128 + 255) / 256, 256, 0, stream>>>(W_embed, WembT);
    pad_cvt_x_kernel<<<((size_t)Nn * 128 + 255) / 256, 256, 0, stream>>>(x, xb, Nn);

    int gmb = (Nn + 127) / 128;
    // embed via MFMA: h32 + hb = xb @ WembT^T
    gemm_mfma<3><<<dim3(gmb, D / 64), 256, 0, stream>>>(
        xb, WembT, nullptr, h32, hb, Nn, D, D);

    for (int l = 0; l < NL; ++l) {
        gemm_mfma<0><<<dim3(gmb, QKV / 64), 256, 0, stream>>>(
            hb, WqkvT + (size_t)l * QKV * D, nullptr, nullptr, qkvb, Nn, QKV, D);
        attn_kernel<<<(Nn + 3) / 4, 256, 0, stream>>>(qkvb, off, csr_src, aggb, Nn);
        gemm_mfma<2><<<dim3(gmb, D / 64), 256, 0, stream>>>(
            aggb, WoutT + (size_t)l * D * D, b_out + (size_t)l * D, h32, hb, Nn, D, D);
        gemm_mfma<1><<<dim3(gmb, DFF / 64), 256, 0, stream>>>(
            hb, W1T + (size_t)l * D * DFF, b1 + (size_t)l * DFF, nullptr, ff1b, Nn, DFF, D);
        gemm_mfma<2><<<dim3(gmb, D / 64), 256, 0, stream>>>(
            ff1b, W2T + (size_t)l * DFF * D, b2 + (size_t)l * D, h32, hb, Nn, D, DFF);
    }

    group_bounds_kernel<<<1, 128, 0, stream>>>(batch, Nn, gstart);
    pool_stage1<<<dim3(NG, 8), 256, 0, stream>>>(h32, gstart, pws);
    pool_stage2<<<NG, 128, 0, stream>>>(pws, gstart, (float*)d_out);
}

// Round 5
// 664.246 us; speedup vs baseline: 5.0378x; 1.1530x over previous
//
#include <hip/hip_runtime.h>
#include <hip/hip_bf16.h>
#include <math.h>

#define D 128
#define NH 8
#define DFF 512
#define NG 64
#define NL 4
#define FIN 100
#define SCALE 0.25f
#define QKV 384

typedef __attribute__((ext_vector_type(8))) short short8;
typedef __attribute__((ext_vector_type(4))) float f32x4;

__device__ inline unsigned short f2bf(float v) {
    __hip_bfloat16 b = __float2bfloat16(v);
    return *reinterpret_cast<unsigned short*>(&b);
}

// ---------------- CSR build ----------------
__global__ void count_kernel(const int* __restrict__ dst, int* __restrict__ cnt, int E) {
    int e = blockIdx.x * 256 + threadIdx.x;
    if (e < E) atomicAdd(&cnt[dst[e]], 1);
}

__global__ __launch_bounds__(1024) void scan_block_kernel(const int* __restrict__ cnt,
        int* __restrict__ incl, int* __restrict__ partials, int n) {
    __shared__ int s[1024];
    int tid = threadIdx.x;
    int gid = blockIdx.x * 1024 + tid;
    int val = (gid < n) ? cnt[gid] : 0;
    s[tid] = val;
    __syncthreads();
    for (int o = 1; o < 1024; o <<= 1) {
        int t = (tid >= o) ? s[tid - o] : 0;
        __syncthreads();
        s[tid] += t;
        __syncthreads();
    }
    if (gid < n) incl[gid] = s[tid];
    if (tid == 1023) partials[blockIdx.x] = s[1023];
}

__global__ void scan_partials_kernel(int* __restrict__ partials, int nb) {
    if (threadIdx.x == 0 && blockIdx.x == 0) {
        int run = 0;
        for (int i = 0; i < nb; ++i) { int t = partials[i]; partials[i] = run; run += t; }
    }
}

__global__ void finalize_off_kernel(const int* __restrict__ cnt, const int* __restrict__ incl,
        const int* __restrict__ partials, int* __restrict__ off, int* __restrict__ cur,
        int n, int E) {
    int gid = blockIdx.x * 256 + threadIdx.x;
    if (gid < n) {
        int v = incl[gid] - cnt[gid] + partials[gid >> 10];
        off[gid] = v;
        cur[gid] = v;
    }
    if (gid == 0) off[n] = E;
}

__global__ void scatter_kernel(const int* __restrict__ src, const int* __restrict__ dst,
        int* __restrict__ cur, int* __restrict__ csr_src, int E) {
    int e = blockIdx.x * 256 + threadIdx.x;
    if (e < E) {
        int p = atomicAdd(&cur[dst[e]], 1);
        csr_src[p] = src[e];
    }
}

// ---- weight transpose + bf16 convert: W[K][N] -> Bt[n][k] (out layer stride ldl) ----
__global__ void transpose_cvt_kernel(const float* __restrict__ W, __hip_bfloat16* __restrict__ Bt,
        int K, int N, int ldl) {
    int l = blockIdx.y;
    const float* w = W + (size_t)l * K * N;
    __hip_bfloat16* bt = Bt + (size_t)l * ldl;
    int idx = blockIdx.x * 256 + threadIdx.x;
    if (idx >= K * N) return;
    int n = idx / K, k = idx - n * K;
    bt[(size_t)n * K + k] = __float2bfloat16(w[(size_t)k * N + n]);
}

// ---- embed input pad+cvt: x[N][100] f32 -> xb[N][128] bf16 (zero-padded) ----
__global__ void pad_cvt_x_kernel(const float* __restrict__ x, __hip_bfloat16* __restrict__ xb, int n) {
    int idx = blockIdx.x * 256 + threadIdx.x;
    if (idx >= n * 128) return;
    int r = idx >> 7, c = idx & 127;
    xb[idx] = (c < FIN) ? __float2bfloat16(x[(size_t)r * FIN + c]) : __float2bfloat16(0.f);
}

// ---- W_embed[100][128] -> WembT[128][128] bf16 (k zero-padded) ----
__global__ void wembT_kernel(const float* __restrict__ W, __hip_bfloat16* __restrict__ Bt) {
    int idx = blockIdx.x * 256 + threadIdx.x;
    if (idx >= 128 * 128) return;
    int n = idx >> 7, k = idx & 127;
    Bt[idx] = (k < FIN) ? __float2bfloat16(W[(size_t)k * 128 + n]) : __float2bfloat16(0.f);
}

// ---------------- bf16 MFMA GEMM: A[M,K] @ Bt[N,K]^T, tile 128x64, BK=64 ----------------
// EPI 0: Cb = bf16(acc)
// EPI 3: Cf = acc; Cb = bf16(acc)   (dual write, no bias)
template<int EPI>
__global__ __launch_bounds__(256) void gemm_mfma(
        const __hip_bfloat16* __restrict__ A, const __hip_bfloat16* __restrict__ Bt,
        const float* __restrict__ bias,
        float* __restrict__ Cf, __hip_bfloat16* __restrict__ Cb,
        int M, int N, int K) {
    __shared__ __align__(16) unsigned short As[128][64];
    __shared__ __align__(16) unsigned short Bs[64][64];
    int t = threadIdx.x;
    int wave = t >> 6, lane = t & 63;
    int row0 = blockIdx.x * 128, col0 = blockIdx.y * 64;
    f32x4 acc[2][4] = {};

    int sr = t >> 3;
    int sc = t & 7;

    for (int k0 = 0; k0 < K; k0 += 64) {
#pragma unroll
        for (int i = 0; i < 4; ++i) {
            int r = i * 32 + sr;
            int gr = row0 + r;
            if (gr >= M) gr = M - 1;
            *reinterpret_cast<short8*>(&As[r][(sc ^ (r & 7)) << 3]) =
                *reinterpret_cast<const short8*>(&A[(size_t)gr * K + k0 + (sc << 3)]);
        }
#pragma unroll
        for (int i = 0; i < 2; ++i) {
            int r = i * 32 + sr;
            *reinterpret_cast<short8*>(&Bs[r][(sc ^ (r & 7)) << 3]) =
                *reinterpret_cast<const short8*>(&Bt[(size_t)(col0 + r) * K + k0 + (sc << 3)]);
        }
        __syncthreads();
#pragma unroll
        for (int kk = 0; kk < 64; kk += 32) {
            int lr = lane & 15;
            int kc = (kk >> 3) + (lane >> 4);
            short8 a[2], b[4];
#pragma unroll
            for (int m = 0; m < 2; ++m) {
                int r = wave * 32 + m * 16 + lr;
                a[m] = *reinterpret_cast<const short8*>(&As[r][(kc ^ (r & 7)) << 3]);
            }
#pragma unroll
            for (int n = 0; n < 4; ++n) {
                int r = n * 16 + lr;
                b[n] = *reinterpret_cast<const short8*>(&Bs[r][(kc ^ (r & 7)) << 3]);
            }
#pragma unroll
            for (int m = 0; m < 2; ++m)
#pragma unroll
                for (int n = 0; n < 4; ++n)
                    acc[m][n] = __builtin_amdgcn_mfma_f32_16x16x32_bf16(a[m], b[n], acc[m][n], 0, 0, 0);
        }
        __syncthreads();
    }

    int lr = lane & 15, rg = (lane >> 4) * 4;
#pragma unroll
    for (int m = 0; m < 2; ++m) {
#pragma unroll
        for (int n = 0; n < 4; ++n) {
            int col = col0 + n * 16 + lr;
#pragma unroll
            for (int j = 0; j < 4; ++j) {
                int row = row0 + wave * 32 + m * 16 + rg + j;
                if (row < M) {
                    float val = acc[m][n][j];
                    if (EPI == 0) {
                        Cb[(size_t)row * N + col] = __float2bfloat16(val);
                    } else {
                        Cf[(size_t)row * N + col] = val;
                        Cb[(size_t)row * N + col] = __float2bfloat16(val);
                    }
                }
            }
        }
    }
}

// ======== fused out-proj + residual + FFN (chunk-streamed) ========
// h' = h32 + agg@WoutT^T + b_out ; h'' = h' + relu(h'@W1T^T+b1)@W2T^T + b2
// writes h32 (f32) and hb (bf16). LDS (dynamic 80KB):
//   region0 [128][128] : A-stage (aggb) -> reused in-place as hbT (bf16 h')
//   region1 [128][128] : phase1 WoutT ; phase2 W1s[64][128] + ff1s[128][64]
//   region2 [128][64]  : W2s chunk
__global__ __launch_bounds__(256) void fused_out_ffn(
        const __hip_bfloat16* __restrict__ aggb, const __hip_bfloat16* __restrict__ WoutT,
        const float* __restrict__ b_out,
        const __hip_bfloat16* __restrict__ W1T, const float* __restrict__ b1,
        const __hip_bfloat16* __restrict__ W2T, const float* __restrict__ b2,
        float* __restrict__ h32, __hip_bfloat16* __restrict__ hb, int M) {
    extern __shared__ __align__(16) unsigned short smem[];
    unsigned short* As  = smem;              // 16384 shorts
    unsigned short* Bs  = smem + 16384;      // 16384 shorts
    unsigned short* W1s = Bs;                // [64][128] = 8192
    unsigned short* ff1s = Bs + 8192;        // [128][64] = 8192
    unsigned short* W2s = smem + 32768;      // [128][64] = 8192

    int t = threadIdx.x;
    int wave = t >> 6, lane = t & 63;
    int lr = lane & 15, lg = lane >> 4;
    int row0 = blockIdx.x * 128;

    // ---- stage A (agg tile) and B (WoutT), both [128][128], 16B-chunk XOR swizzle ----
#pragma unroll
    for (int i = 0; i < 8; ++i) {
        int idx = t + i * 256;          // 0..2047
        int r = idx >> 4, ch = idx & 15;
        int gr = row0 + r; if (gr >= M) gr = M - 1;
        *reinterpret_cast<short8*>(&As[r * 128 + ((ch ^ (r & 7)) << 3)]) =
            *reinterpret_cast<const short8*>(&aggb[(size_t)gr * 128 + ch * 8]);
        *reinterpret_cast<short8*>(&Bs[r * 128 + ((ch ^ (r & 7)) << 3)]) =
            *reinterpret_cast<const short8*>(&WoutT[(size_t)r * 128 + ch * 8]);
    }
    __syncthreads();

    // ---- phase 1: out = A @ WoutT^T  (K=128, full N=128), wave owns 32 rows ----
    f32x4 acc1[2][8] = {};
#pragma unroll
    for (int kk4 = 0; kk4 < 4; ++kk4) {
        int kc = kk4 * 4 + lg;
        short8 a[2], b[8];
#pragma unroll
        for (int m = 0; m < 2; ++m) {
            int r = wave * 32 + m * 16 + lr;
            a[m] = *reinterpret_cast<const short8*>(&As[r * 128 + ((kc ^ (r & 7)) << 3)]);
        }
#pragma unroll
        for (int n = 0; n < 8; ++n) {
            int r = n * 16 + lr;
            b[n] = *reinterpret_cast<const short8*>(&Bs[r * 128 + ((kc ^ (r & 7)) << 3)]);
        }
#pragma unroll
        for (int m = 0; m < 2; ++m)
#pragma unroll
            for (int n = 0; n < 8; ++n)
                acc1[m][n] = __builtin_amdgcn_mfma_f32_16x16x32_bf16(a[m], b[n], acc1[m][n], 0, 0, 0);
    }

    // ---- phase 1 epilogue: h' = out + b_out + h32 ; write h32, hbT(LDS, in-place over As) ----
#pragma unroll
    for (int m = 0; m < 2; ++m) {
#pragma unroll
        for (int n = 0; n < 8; ++n) {
            int col = n * 16 + lr;
            float bo = b_out[col];
#pragma unroll
            for (int j = 0; j < 4; ++j) {
                int rl = wave * 32 + m * 16 + lg * 4 + j;
                int row = row0 + rl;
                float hv = (row < M) ? h32[(size_t)row * 128 + col] : 0.f;
                float val = acc1[m][n][j] + bo + hv;
                if (row < M) h32[(size_t)row * 128 + col] = val;
                As[rl * 128 + (((col >> 3) ^ (rl & 7)) << 3) + (col & 7)] = f2bf(val);
            }
        }
    }

    // ---- phase 2: FFN chunk-streamed over DFF in 64-col chunks ----
    f32x4 h2acc[2][8] = {};
    for (int c = 0; c < 8; ++c) {
        __syncthreads();   // everyone done reading W1s/ff1s/W2s (or Bs when c==0)
        // stage W1s [64][128] <- W1T rows c*64..c*64+63
#pragma unroll
        for (int i = 0; i < 4; ++i) {
            int idx = t + i * 256;      // 0..1023
            int r = idx >> 4, ch = idx & 15;
            *reinterpret_cast<short8*>(&W1s[r * 128 + ((ch ^ (r & 7)) << 3)]) =
                *reinterpret_cast<const short8*>(&W1T[((size_t)(c * 64 + r)) * 128 + ch * 8]);
        }
        // stage W2s [128][64] <- W2T[:, c*64..c*64+63]
#pragma unroll
        for (int i = 0; i < 4; ++i) {
            int idx = t + i * 256;
            int r = idx >> 3, ch = idx & 7;
            *reinterpret_cast<short8*>(&W2s[r * 64 + ((ch ^ (r & 7)) << 3)]) =
                *reinterpret_cast<const short8*>(&W2T[(size_t)r * 512 + c * 64 + ch * 8]);
        }
        __syncthreads();
        // ffn1 chunk: ff1 = relu(hbT @ W1s^T + b1)
        f32x4 acc2[2][4] = {};
#pragma unroll
        for (int kk4 = 0; kk4 < 4; ++kk4) {
            int kc = kk4 * 4 + lg;
            short8 a[2], b[4];
#pragma unroll
            for (int m = 0; m < 2; ++m) {
                int r = wave * 32 + m * 16 + lr;
                a[m] = *reinterpret_cast<const short8*>(&As[r * 128 + ((kc ^ (r & 7)) << 3)]);
            }
#pragma unroll
            for (int n = 0; n < 4; ++n) {
                int r = n * 16 + lr;
                b[n] = *reinterpret_cast<const short8*>(&W1s[r * 128 + ((kc ^ (r & 7)) << 3)]);
            }
#pragma unroll
            for (int m = 0; m < 2; ++m)
#pragma unroll
                for (int n = 0; n < 4; ++n)
                    acc2[m][n] = __builtin_amdgcn_mfma_f32_16x16x32_bf16(a[m], b[n], acc2[m][n], 0, 0, 0);
        }
        // relu + bias -> ff1s (own rows only)
#pragma unroll
        for (int m = 0; m < 2; ++m) {
#pragma unroll
            for (int n = 0; n < 4; ++n) {
                int col = n * 16 + lr;
                float bb = b1[c * 64 + col];
#pragma unroll
                for (int j = 0; j < 4; ++j) {
                    int rl = wave * 32 + m * 16 + lg * 4 + j;
                    float val = fmaxf(acc2[m][n][j] + bb, 0.f);
                    ff1s[rl * 64 + (((col >> 3) ^ (rl & 7)) << 3) + (col & 7)] = f2bf(val);
                }
            }
        }
        // ffn2 partial: h2acc += ff1s @ W2s^T  (K=64)
#pragma unroll
        for (int kk4 = 0; kk4 < 2; ++kk4) {
            int kc = kk4 * 4 + lg;
            short8 a[2], b[8];
#pragma unroll
            for (int m = 0; m < 2; ++m) {
                int r = wave * 32 + m * 16 + lr;
                a[m] = *reinterpret_cast<const short8*>(&ff1s[r * 64 + ((kc ^ (r & 7)) << 3)]);
            }
#pragma unroll
            for (int n = 0; n < 8; ++n) {
                int r = n * 16 + lr;
                b[n] = *reinterpret_cast<const short8*>(&W2s[r * 64 + ((kc ^ (r & 7)) << 3)]);
            }
#pragma unroll
            for (int m = 0; m < 2; ++m)
#pragma unroll
                for (int n = 0; n < 8; ++n)
                    h2acc[m][n] = __builtin_amdgcn_mfma_f32_16x16x32_bf16(a[m], b[n], h2acc[m][n], 0, 0, 0);
        }
    }

    // ---- phase 3: h'' = h2acc + b2 + h' (h32 re-read, L2-hot) ----
#pragma unroll
    for (int m = 0; m < 2; ++m) {
#pragma unroll
        for (int n = 0; n < 8; ++n) {
            int col = n * 16 + lr;
            float bb = b2[col];
#pragma unroll
            for (int j = 0; j < 4; ++j) {
                int row = row0 + wave * 32 + m * 16 + lg * 4 + j;
                if (row < M) {
                    float val = h2acc[m][n][j] + bb + h32[(size_t)row * 128 + col];
                    h32[(size_t)row * 128 + col] = val;
                    hb[(size_t)row * 128 + col] = __float2bfloat16(val);
                }
            }
        }
    }
}

// ------- attention: wave/dst, 4-edge blocked online softmax, fused qkv rows -------
__global__ __launch_bounds__(256) void attn_kernel(const __hip_bfloat16* __restrict__ qkvb,
        const int* __restrict__ off, const int* __restrict__ csr_src,
        __hip_bfloat16* __restrict__ aggb, int n) {
    int wave = threadIdx.x >> 6;
    int lane = threadIdx.x & 63;
    int i = blockIdx.x * 4 + wave;
    if (i >= n) return;
    const unsigned* qv = reinterpret_cast<const unsigned*>(qkvb);
    unsigned ku = qv[(size_t)i * 192 + 64 + lane];
    float kx = __uint_as_float(ku << 16);
    float ky = __uint_as_float(ku & 0xffff0000u);
    int e0 = off[i], e1 = off[i + 1];
    float m = -INFINITY, ssum = 0.f, ax = 0.f, ay = 0.f;
    int e = e0;
    for (; e + 4 <= e1; e += 4) {
        int s0 = csr_src[e], s1 = csr_src[e + 1], s2 = csr_src[e + 2], s3 = csr_src[e + 3];
        unsigned q0 = qv[(size_t)s0 * 192 + lane];
        unsigned q1 = qv[(size_t)s1 * 192 + lane];
        unsigned q2 = qv[(size_t)s2 * 192 + lane];
        unsigned q3 = qv[(size_t)s3 * 192 + lane];
        unsigned w0 = qv[(size_t)s0 * 192 + 128 + lane];
        unsigned w1 = qv[(size_t)s1 * 192 + 128 + lane];
        unsigned w2 = qv[(size_t)s2 * 192 + 128 + lane];
        unsigned w3 = qv[(size_t)s3 * 192 + 128 + lane];
        float l0 = __uint_as_float(q0 << 16) * kx + __uint_as_float(q0 & 0xffff0000u) * ky;
        float l1 = __uint_as_float(q1 << 16) * kx + __uint_as_float(q1 & 0xffff0000u) * ky;
        float l2 = __uint_as_float(q2 << 16) * kx + __uint_as_float(q2 & 0xffff0000u) * ky;
        float l3 = __uint_as_float(q3 << 16) * kx + __uint_as_float(q3 & 0xffff0000u) * ky;
        l0 += __shfl_xor(l0, 1); l1 += __shfl_xor(l1, 1); l2 += __shfl_xor(l2, 1); l3 += __shfl_xor(l3, 1);
        l0 += __shfl_xor(l0, 2); l1 += __shfl_xor(l1, 2); l2 += __shfl_xor(l2, 2); l3 += __shfl_xor(l3, 2);
        l0 += __shfl_xor(l0, 4); l1 += __shfl_xor(l1, 4); l2 += __shfl_xor(l2, 4); l3 += __shfl_xor(l3, 4);
        l0 *= SCALE; l1 *= SCALE; l2 *= SCALE; l3 *= SCALE;
        float mx = fmaxf(fmaxf(l0, l1), fmaxf(l2, l3));
        float mn = fmaxf(m, mx);
        float corr = __expf(m - mn);
        float p0 = __expf(l0 - mn);
        float p1 = __expf(l1 - mn);
        float p2 = __expf(l2 - mn);
        float p3 = __expf(l3 - mn);
        ssum = ssum * corr + ((p0 + p1) + (p2 + p3));
        ax = ax * corr + p0 * __uint_as_float(w0 << 16) + p1 * __uint_as_float(w1 << 16)
                       + p2 * __uint_as_float(w2 << 16) + p3 * __uint_as_float(w3 << 16);
        ay = ay * corr + p0 * __uint_as_float(w0 & 0xffff0000u) + p1 * __uint_as_float(w1 & 0xffff0000u)
                       + p2 * __uint_as_float(w2 & 0xffff0000u) + p3 * __uint_as_float(w3 & 0xffff0000u);
        m = mn;
    }
    for (; e < e1; ++e) {
        int s0 = csr_src[e];
        unsigned q0 = qv[(size_t)s0 * 192 + lane];
        unsigned w0 = qv[(size_t)s0 * 192 + 128 + lane];
        float l0 = __uint_as_float(q0 << 16) * kx + __uint_as_float(q0 & 0xffff0000u) * ky;
        l0 += __shfl_xor(l0, 1); l0 += __shfl_xor(l0, 2); l0 += __shfl_xor(l0, 4);
        l0 *= SCALE;
        float mn = fmaxf(m, l0);
        float corr = __expf(m - mn);
        float pe = __expf(l0 - mn);
        ssum = ssum * corr + pe;
        ax = ax * corr + pe * __uint_as_float(w0 << 16);
        ay = ay * corr + pe * __uint_as_float(w0 & 0xffff0000u);
        m = mn;
    }
    float inv = (ssum > 0.f) ? 1.f / ssum : 0.f;
    __hip_bfloat162 o;
    o.x = __float2bfloat16(ax * inv);
    o.y = __float2bfloat16(ay * inv);
    *reinterpret_cast<__hip_bfloat162*>(aggb + (size_t)i * 128 + lane * 2) = o;
}

// ---------------- pooling (deterministic two-stage, batch sorted) ----------------
__global__ void group_bounds_kernel(const int* __restrict__ batch, int n, int* __restrict__ gstart) {
    int g = threadIdx.x;
    if (g > NG) return;
    int lo = 0, hi = n;
    while (lo < hi) {
        int mid = (lo + hi) >> 1;
        if (batch[mid] < g) lo = mid + 1; else hi = mid;
    }
    gstart[g] = lo;
}

__global__ __launch_bounds__(256) void pool_stage1(const float* __restrict__ h,
        const int* __restrict__ gstart, float* __restrict__ pws) {
    int g = blockIdx.x, sub = blockIdx.y;
    int s = gstart[g], e = gstart[g + 1];
    int c = threadIdx.x & 127;
    int half = threadIdx.x >> 7;
    float acc = 0.f;
    for (int r = s + sub * 2 + half; r < e; r += 16)
        acc += h[(size_t)r * 128 + c];
    __shared__ float tmp[2][128];
    tmp[half][c] = acc;
    __syncthreads();
    if (half == 0)
        pws[((size_t)g * 8 + sub) * 128 + c] = tmp[0][c] + tmp[1][c];
}

__global__ void pool_stage2(const float* __restrict__ pws, const int* __restrict__ gstart,
        float* __restrict__ out) {
    int g = blockIdx.x, c = threadIdx.x;
    float s = 0.f;
#pragma unroll
    for (int i = 0; i < 8; ++i) s += pws[((size_t)g * 8 + i) * 128 + c];
    float cntf = (float)(gstart[g + 1] - gstart[g]);
    out[(size_t)g * 128 + c] = s / fmaxf(cntf, 1.f);
}

extern "C" void kernel_launch(void* const* d_in, const int* in_sizes, int n_in,
                              void* d_out, int out_size, void* d_ws, size_t ws_size,
                              hipStream_t stream) {
    const float* x = (const float*)d_in[0];
    const int* ei = (const int*)d_in[1];
    const int* batch = (const int*)d_in[2];
    const float* W_embed = (const float*)d_in[3];
    const float* Wqk = (const float*)d_in[4];
    const float* Wv = (const float*)d_in[5];
    const float* Wout = (const float*)d_in[6];
    const float* b_out = (const float*)d_in[7];
    const float* W1 = (const float*)d_in[8];
    const float* b1 = (const float*)d_in[9];
    const float* W2 = (const float*)d_in[10];
    const float* b2 = (const float*)d_in[11];

    int Nn = in_sizes[2];
    int E = in_sizes[1] / 2;

    char* p = (char*)d_ws;
    auto alloc = [&](size_t bytes) {
        char* r = p;
        p += (bytes + 255) & ~(size_t)255;
        return r;
    };
    float* h32 = (float*)alloc((size_t)Nn * D * 4);
    __hip_bfloat16* hb = (__hip_bfloat16*)alloc((size_t)Nn * D * 2);
    __hip_bfloat16* aggb = (__hip_bfloat16*)alloc((size_t)Nn * D * 2);
    __hip_bfloat16* qkvb = (__hip_bfloat16*)alloc((size_t)Nn * QKV * 2);
    __hip_bfloat16* xb = (__hip_bfloat16*)alloc((size_t)Nn * D * 2);
    __hip_bfloat16* WembT = (__hip_bfloat16*)alloc((size_t)D * D * 2);
    __hip_bfloat16* WqkvT = (__hip_bfloat16*)alloc((size_t)NL * QKV * D * 2);
    __hip_bfloat16* WoutT = (__hip_bfloat16*)alloc((size_t)NL * D * D * 2);
    __hip_bfloat16* W1T = (__hip_bfloat16*)alloc((size_t)NL * D * DFF * 2);
    __hip_bfloat16* W2T = (__hip_bfloat16*)alloc((size_t)NL * DFF * D * 2);
    int* csr_src = (int*)alloc((size_t)E * 4);
    int* cnt = (int*)alloc((size_t)Nn * 4);
    int* incl = (int*)alloc((size_t)Nn * 4);
    int* off = (int*)alloc(((size_t)Nn + 1) * 4);
    int* cur = (int*)alloc((size_t)Nn * 4);
    int* partials = (int*)alloc(1024 * 4);
    int* gstart = (int*)alloc((NG + 1) * 4);
    float* pws = (float*)alloc((size_t)NG * 8 * 128 * 4);

    const int* e_src = ei;
    const int* e_dst = ei + E;

    // CSR build (by dst)
    hipMemsetAsync(cnt, 0, (size_t)Nn * 4, stream);
    count_kernel<<<(E + 255) / 256, 256, 0, stream>>>(e_dst, cnt, E);
    int nsb = (Nn + 1023) / 1024;
    scan_block_kernel<<<nsb, 1024, 0, stream>>>(cnt, incl, partials, Nn);
    scan_partials_kernel<<<1, 64, 0, stream>>>(partials, nsb);
    finalize_off_kernel<<<(Nn + 255) / 256, 256, 0, stream>>>(cnt, incl, partials, off, cur, Nn, E);
    scatter_kernel<<<(E + 255) / 256, 256, 0, stream>>>(e_src, e_dst, cur, csr_src, E);

    // weight prep
    transpose_cvt_kernel<<<dim3((2 * D * D + 255) / 256, NL), 256, 0, stream>>>(
        Wqk, WqkvT, D, 2 * D, QKV * D);
    transpose_cvt_kernel<<<dim3((D * D + 255) / 256, NL), 256, 0, stream>>>(
        Wv, WqkvT + (size_t)2 * D * D, D, D, QKV * D);
    transpose_cvt_kernel<<<dim3((D * D + 255) / 256, NL), 256, 0, stream>>>(
        Wout, WoutT, D, D, D * D);
    transpose_cvt_kernel<<<dim3((D * DFF + 255) / 256, NL), 256, 0, stream>>>(
        W1, W1T, D, DFF, D * DFF);
    transpose_cvt_kernel<<<dim3((DFF * D + 255) / 256, NL), 256, 0, stream>>>(
        W2, W2T, DFF, D, DFF * D);
    wembT_kernel<<<(128 * 128 + 255) / 256, 256, 0, stream>>>(W_embed, WembT);
    pad_cvt_x_kernel<<<((size_t)Nn * 128 + 255) / 256, 256, 0, stream>>>(x, xb, Nn);

    int gmb = (Nn + 127) / 128;
    // embed via MFMA: h32 + hb = xb @ WembT^T
    gemm_mfma<3><<<dim3(gmb, D / 64), 256, 0, stream>>>(
        xb, WembT, nullptr, h32, hb, Nn, D, D);

    size_t fused_lds = (size_t)(16384 + 16384 + 8192) * sizeof(unsigned short); // 80 KB

    for (int l = 0; l < NL; ++l) {
        gemm_mfma<0><<<dim3(gmb, QKV / 64), 256, 0, stream>>>(
            hb, WqkvT + (size_t)l * QKV * D, nullptr, nullptr, qkvb, Nn, QKV, D);
        attn_kernel<<<(Nn + 3) / 4, 256, 0, stream>>>(qkvb, off, csr_src, aggb, Nn);
        fused_out_ffn<<<gmb, 256, fused_lds, stream>>>(
            aggb, WoutT + (size_t)l * D * D, b_out + (size_t)l * D,
            W1T + (size_t)l * D * DFF, b1 + (size_t)l * DFF,
            W2T + (size_t)l * DFF * D, b2 + (size_t)l * D,
            h32, hb, Nn);
    }

    group_bounds_kernel<<<1, 128, 0, stream>>>(batch, Nn, gstart);
    pool_stage1<<<dim3(NG, 8), 256, 0, stream>>>(h32, gstart, pws);
    pool_stage2<<<NG, 128, 0, stream>>>(pws, gstart, (float*)d_out);
}